// Round 7
// baseline (3151.078 us; speedup 1.0000x reference)
//
#include <hip/hip_runtime.h>

// ---------------------------------------------------------------------------
// 2-layer GCN forward:  out = A_norm * relu(A_norm * (x@W1) + b1) @ W2 + b2
// A_norm = D^-1/2 (A+I) D^-1/2, applied as dinv[dst] * sum( dinv[src]*m[src] )
// m bf16 (dinv[src] folded), SLICE-MAJOR [8][n+1][16]: 3.2MB slice pinned to
// one XCD's L2 via bid&7. agg: wave = 8 consecutive rows, coalesced csr batch
// + bpermute, 8-lane groups gather 32B slice-rows, ds_add_f32 into LDS acc.
// csr entry = src | (dst&7)<<20. GEMMs on MFMA split-bf16 (fp32 accuracy).
// ---------------------------------------------------------------------------

#define RB    9
#define RANGE 512
#define CAPB  16384
#define CHUNK 8192
#define ASTR  17   // LDS acc row stride (floats) - bank-conflict-free

typedef __attribute__((ext_vector_type(8))) short bf16x8;
typedef __attribute__((ext_vector_type(4))) float f32x4;

__device__ inline float bf_lo(unsigned w) { return __uint_as_float(w << 16); }
__device__ inline float bf_hi(unsigned w) { return __uint_as_float(w & 0xffff0000u); }
__device__ inline unsigned bf16pair(float lo, float hi) {  // RNE pack
    unsigned a = __float_as_uint(lo), b = __float_as_uint(hi);
    a += 0x7fffu + ((a >> 16) & 1u);
    b += 0x7fffu + ((b >> 16) & 1u);
    return (a >> 16) | (b & 0xffff0000u);
}
__device__ inline unsigned short bf16rne(float f) {
    unsigned u = __float_as_uint(f);
    u += 0x7fffu + ((u >> 16) & 1u);
    return (unsigned short)(u >> 16);
}
__device__ inline float bf2f(unsigned short h) { return __uint_as_float(((unsigned)h) << 16); }

__device__ inline void pack_one(int idx, const float* __restrict__ W,
                                uint4* __restrict__ Bhi, uint4* __restrict__ Blo) {
    int lane = idx & 63, ks = (idx >> 6) & 3, nt = idx >> 8;
    int j = nt * 16 + (lane & 15);
    int k0 = ks * 32 + ((lane >> 4) & 3) * 8;
    unsigned hi[4], lo[4];
#pragma unroll
    for (int p = 0; p < 4; p++) {
        float w0 = W[(size_t)(k0 + 2 * p) * 128 + j];
        float w1 = W[(size_t)(k0 + 2 * p + 1) * 128 + j];
        unsigned short h0 = bf16rne(w0), h1 = bf16rne(w1);
        unsigned short l0 = bf16rne(w0 - bf2f(h0)), l1 = bf16rne(w1 - bf2f(h1));
        hi[p] = (unsigned)h0 | ((unsigned)h1 << 16);
        lo[p] = (unsigned)l0 | ((unsigned)l1 << 16);
    }
    Bhi[idx] = make_uint4(hi[0], hi[1], hi[2], hi[3]);
    Blo[idx] = make_uint4(lo[0], lo[1], lo[2], lo[3]);
}

// --- fused setup: detect dtype | init gcur | pack W1,W2 | zero pad row -----
__global__ __launch_bounds__(256) void setup(const unsigned* __restrict__ ei, int E,
                                             int* __restrict__ flag,
                                             unsigned* __restrict__ gcur, int NB,
                                             const float* __restrict__ W1,
                                             uint4* __restrict__ Bhi1, uint4* __restrict__ Blo1,
                                             const float* __restrict__ W2,
                                             uint4* __restrict__ Bhi2, uint4* __restrict__ Blo2,
                                             unsigned* __restrict__ mm, int n, int mstride) {
    const int b = blockIdx.x, t = threadIdx.x;
    if (b == 0) {
        __shared__ int nz;
        if (t == 0) nz = 0;
        __syncthreads();
        int samples = E < 2048 ? E : 2048;
        int cnt = 0;
        for (int i = t; i < samples; i += 256)
            if (ei[2 * i + 1] != 0u) cnt++;
        if (cnt) atomicAdd(&nz, cnt);
        __syncthreads();
        if (t == 0) *flag = (nz == 0) ? 1 : 0;  // all high words zero -> int64
    } else if (b <= 2) {
        int i = (b - 1) * 256 + t;
        if (i < NB) gcur[i] = (unsigned)i * CAPB;
    } else if (b <= 10) {
        pack_one((b - 3) * 256 + t, W1, Bhi1, Blo1);
    } else if (b <= 18) {
        pack_one((b - 11) * 256 + t, W2, Bhi2, Blo2);
    } else {
        if (t < 64) {
            int s = t >> 3, j = t & 7;
            mm[((size_t)s * mstride + n) * 8 + j] = 0u;
        }
    }
}

// --- phase A: edges -> per-bucket record arrays (4B records) ---------------
__global__ __launch_bounds__(256) void bucketA(const unsigned* __restrict__ ei, int E, int n,
                                               const int* __restrict__ flag,
                                               unsigned* __restrict__ gcur,
                                               unsigned* __restrict__ recs) {
    __shared__ unsigned hist[512];
    __shared__ unsigned offs[512];
    const int t = threadIdx.x;
    const int NB = (n + RANGE - 1) >> RB;
    for (int i = t; i < NB; i += 256) hist[i] = 0u;
    __syncthreads();
    const int base = blockIdx.x * CHUNK;
    const bool i64 = (*flag != 0);
    unsigned rec[32], bk[32];
#pragma unroll
    for (int j = 0; j < 32; j++) {
        int i = base + j * 256 + t;
        unsigned bv = 0xffffffffu, rv = 0u;
        if (i < E) {
            unsigned s, d;
            if (i64) { s = ei[2 * (size_t)i]; d = ei[2 * ((size_t)E + i)]; }
            else     { s = ei[i];             d = ei[(size_t)E + i]; }
            bv = d >> RB;
            rv = (s << RB) | (d & (RANGE - 1));
            atomicAdd(&hist[bv], 1u);
        }
        rec[j] = rv; bk[j] = bv;
    }
    __syncthreads();
    for (int b = t; b < NB; b += 256) {
        unsigned h = hist[b];
        offs[b] = h ? atomicAdd(&gcur[b], h) : 0u;
    }
    __syncthreads();
#pragma unroll
    for (int j = 0; j < 32; j++) {
        unsigned b = bk[j];
        if (b != 0xffffffffu) {
            unsigned pos = atomicAdd(&offs[b], 1u);
            if (pos < (b + 1u) * CAPB) recs[pos] = rec[j];
        }
    }
}

// --- phase A2: per-bucket degree + dinv (self-loop included) ---------------
__global__ __launch_bounds__(256) void bucket_deg(const unsigned* __restrict__ gcur,
                                                  const unsigned* __restrict__ recs,
                                                  unsigned* __restrict__ deg,
                                                  float* __restrict__ dinv, int n) {
    __shared__ unsigned dl[RANGE];
    const int b = blockIdx.x, t = threadIdx.x;
    const int node0 = b << RB;
    for (int v = t; v < RANGE; v += 256) dl[v] = 1u;
    __syncthreads();
    unsigned base = (unsigned)b * CAPB;
    unsigned cnt = gcur[b] - base; if (cnt > CAPB) cnt = CAPB;
    for (unsigned i = t; i < cnt; i += 256)
        atomicAdd(&dl[recs[base + i] & (RANGE - 1)], 1u);
    __syncthreads();
    for (int v = t; v < RANGE; v += 256)
        if (node0 + v < n) {
            unsigned d = dl[v];
            deg[node0 + v] = d;
            dinv[node0 + v] = rsqrtf((float)d);
        }
}

// --- single-block exclusive scan: deg[n] -> row_off[n+1] -------------------
__global__ __launch_bounds__(1024) void scan_all(const unsigned* __restrict__ deg,
                                                 int* __restrict__ row_off, int n) {
    __shared__ unsigned wsum[16];
    const int t = threadIdx.x;
    const int K = (n + 1023) >> 10;
    const int base = t * K;
    unsigned s = 0;
    for (int k = 0; k < K; k++) {
        int i = base + k;
        if (i < n) s += deg[i];
    }
    const int lane = t & 63, wv = t >> 6;
    unsigned inc = s;
    for (int o = 1; o < 64; o <<= 1) {
        unsigned u = (unsigned)__shfl_up((int)inc, o, 64);
        if (lane >= o) inc += u;
    }
    if (lane == 63) wsum[wv] = inc;
    __syncthreads();
    if (t < 16) {
        unsigned v = wsum[t];
        unsigned in2 = v;
        for (int o = 1; o < 16; o <<= 1) {
            unsigned u = (unsigned)__shfl_up((int)in2, o, 64);
            if (t >= o) in2 += u;
        }
        wsum[t] = in2 - v;  // exclusive
    }
    __syncthreads();
    unsigned excl = wsum[wv] + inc - s;
    for (int k = 0; k < K; k++) {
        int i = base + k;
        if (i < n) { unsigned d = deg[i]; row_off[i] = (int)excl; excl += d; }
    }
    if (t == 1023) row_off[n] = (int)excl;
}

// --- phase B: per-bucket CSR scatter; entry = src | (dst&7)<<20 ------------
__global__ __launch_bounds__(256) void bucket_csr(const unsigned* __restrict__ gcur,
                                                  const unsigned* __restrict__ recs,
                                                  const int* __restrict__ row_off,
                                                  unsigned* __restrict__ csr, int n) {
    __shared__ int cur[RANGE];
    const int b = blockIdx.x, t = threadIdx.x;
    const int node0 = b << RB;
    for (int v = t; v < RANGE; v += 256) {
        int node = node0 + v;
        if (node < n) {
            int ro = row_off[node];
            csr[ro] = (unsigned)node | (((unsigned)node & 7u) << 20);  // self-loop
            cur[v] = ro + 1;
        }
    }
    __syncthreads();
    unsigned base = (unsigned)b * CAPB;
    unsigned cnt = gcur[b] - base; if (cnt > CAPB) cnt = CAPB;
    for (unsigned i = t; i < cnt; i += 256) {
        unsigned r = recs[base + i];
        int pos = atomicAdd(&cur[r & (RANGE - 1)], 1);
        csr[pos] = (r >> RB) | ((r & 7u) << 20);   // src | (dst&7)<<20
    }
}

// --- MFMA GEMM: Mout (slice-major, stride mstride) = dinv[r]*(A[M,128] @ W) -
// SPLIT=1: A fp32 row-major. SPLIT=0: A bf16 slice-major (stride astride).
template <int SPLIT>
__global__ __launch_bounds__(256) void gemm_mfma(const void* __restrict__ Ain, int astride,
                                                 const uint4* __restrict__ Bhi,
                                                 const uint4* __restrict__ Blo,
                                                 const float* __restrict__ dinv,
                                                 unsigned short* __restrict__ Mout,
                                                 int mstride, int M) {
    __shared__ unsigned short Ahi[64 * 128];
    __shared__ unsigned short Alo[SPLIT ? 64 * 128 : 64];
    const int t = threadIdx.x;
    const int row0 = blockIdx.x * 64;
    char* ah8 = (char*)Ahi;
    char* al8 = (char*)Alo;

    if (SPLIT) {
        const float4* A4 = (const float4*)Ain;
#pragma unroll
        for (int it = 0; it < 4; it++) {
            int i = it * 256 + t;
            int r = i >> 4, c8 = i & 15;
            int gr = row0 + r;
            float4 v0 = make_float4(0.f, 0.f, 0.f, 0.f), v1 = v0;
            if (gr < M) { v0 = A4[(size_t)gr * 32 + c8 * 2]; v1 = A4[(size_t)gr * 32 + c8 * 2 + 1]; }
            float f[8] = {v0.x, v0.y, v0.z, v0.w, v1.x, v1.y, v1.z, v1.w};
            unsigned hp[4], lp[4];
#pragma unroll
            for (int p = 0; p < 4; p++) {
                unsigned short h0 = bf16rne(f[2 * p]), h1 = bf16rne(f[2 * p + 1]);
                unsigned short l0 = bf16rne(f[2 * p] - bf2f(h0));
                unsigned short l1 = bf16rne(f[2 * p + 1] - bf2f(h1));
                hp[p] = (unsigned)h0 | ((unsigned)h1 << 16);
                lp[p] = (unsigned)l0 | ((unsigned)l1 << 16);
            }
            int byte = (r * 256 + c8 * 16) ^ ((r & 7) << 4);
            *(uint4*)(ah8 + byte) = make_uint4(hp[0], hp[1], hp[2], hp[3]);
            *(uint4*)(al8 + byte) = make_uint4(lp[0], lp[1], lp[2], lp[3]);
        }
    } else {
        const unsigned short* A = (const unsigned short*)Ain;
#pragma unroll
        for (int it = 0; it < 4; it++) {
            int i = it * 256 + t;
            int half = i & 1, r = (i >> 1) & 63, sl = i >> 7;
            int gr = row0 + r;
            uint4 v = make_uint4(0u, 0u, 0u, 0u);
            if (gr < M) v = *(const uint4*)(A + ((size_t)sl * astride + gr) * 16 + half * 8);
            int byte = (r * 256 + sl * 32 + half * 16) ^ ((r & 7) << 4);
            *(uint4*)(ah8 + byte) = v;
        }
    }
    __syncthreads();

    const int wv = t >> 6, lane = t & 63;
    const int arow = wv * 16 + (lane & 15);
    const int kh = ((lane >> 4) & 3) * 8;
    f32x4 acc[8];
#pragma unroll
    for (int nt = 0; nt < 8; nt++) acc[nt] = (f32x4){0.f, 0.f, 0.f, 0.f};
    float dv[4];
    const int orow0 = row0 + wv * 16 + ((lane >> 4) & 3) * 4;
#pragma unroll
    for (int r = 0; r < 4; r++) {
        int rr = orow0 + r;
        dv[r] = (rr < M) ? dinv[rr] : 0.f;
    }
#pragma unroll
    for (int ks = 0; ks < 4; ks++) {
        int byte = (arow * 256 + (ks * 32 + kh) * 2) ^ ((arow & 7) << 4);
        bf16x8 a_h = *(const bf16x8*)(ah8 + byte);
        bf16x8 a_l;
        if (SPLIT) a_l = *(const bf16x8*)(al8 + byte);
#pragma unroll
        for (int nt = 0; nt < 8; nt++) {
            uint4 bhv = Bhi[(nt * 4 + ks) * 64 + lane];
            uint4 blv = Blo[(nt * 4 + ks) * 64 + lane];
            bf16x8 bh = *(bf16x8*)&bhv;
            bf16x8 bl = *(bf16x8*)&blv;
            acc[nt] = __builtin_amdgcn_mfma_f32_16x16x32_bf16(a_h, bh, acc[nt], 0, 0, 0);
            if (SPLIT) acc[nt] = __builtin_amdgcn_mfma_f32_16x16x32_bf16(a_l, bh, acc[nt], 0, 0, 0);
            acc[nt] = __builtin_amdgcn_mfma_f32_16x16x32_bf16(a_h, bl, acc[nt], 0, 0, 0);
        }
    }
    __syncthreads();
#pragma unroll
    for (int nt = 0; nt < 8; nt++) {
#pragma unroll
        for (int r = 0; r < 4; r++) {
            int lr = wv * 16 + ((lane >> 4) & 3) * 4 + r;
            int byte = (lr * 256 + (nt * 16 + (lane & 15)) * 2) ^ ((lr & 7) << 4);
            *(unsigned short*)(ah8 + byte) = bf16rne(acc[nt][r] * dv[r]);
        }
    }
    __syncthreads();
#pragma unroll
    for (int it = 0; it < 4; it++) {
        int i = it * 256 + t;
        int half = i & 1, r = (i >> 1) & 63, sl = i >> 7;
        int gr = row0 + r;
        if (gr < M) {
            int byte = (r * 256 + sl * 32 + half * 16) ^ ((r & 7) << 4);
            *(uint4*)(Mout + ((size_t)sl * mstride + gr) * 16 + half * 8) = *(uint4*)(ah8 + byte);
        }
    }
}

// --- slice agg: wave = 8 consecutive rows, LDS f32 atomic accumulation -----
__global__ __launch_bounds__(256) void agg_slice(const unsigned* __restrict__ mm,
                                                 const unsigned* __restrict__ csr,
                                                 const int* __restrict__ row_off,
                                                 const float* __restrict__ dinv,
                                                 const float* __restrict__ bias,
                                                 void* __restrict__ outp, int n,
                                                 int mstride, int mode) {
    __shared__ float acc[32 * ASTR];
    const int s = blockIdx.x & 7;
    const int chunk = blockIdx.x >> 3;
    const int t = threadIdx.x;
    const int wid = t >> 6, lane = t & 63;
    const int g = lane >> 3, j = lane & 7;
    const unsigned* ms = mm + (size_t)s * mstride * 8;
    const int vb = chunk * 32;

    acc[t] = 0.f;
    acc[t + 256] = 0.f;
    if (t < 32 * ASTR - 512) acc[t + 512] = 0.f;
    __syncthreads();

    const int v0 = vb + wid * 8;
    if (v0 < n) {
        int v8 = v0 + 8; if (v8 > n) v8 = n;
        int S = row_off[v0];
        int Send = row_off[v8];
        float* accw = &acc[wid * 8 * ASTR];
        for (int p = S; p < Send; p += 64) {
            unsigned sv = (unsigned)n;  // sentinel: src=n (zero pad row), lr=0
            if (p + lane < Send) sv = csr[p + lane];
#pragma unroll
            for (int st = 0; st < 8; st++) {
                unsigned e = (unsigned)__shfl((int)sv, st * 8 + g);
                unsigned src = e & 0xFFFFFu;
                int lr = (int)((e >> 20) & 7u);
                unsigned w = ms[(size_t)src * 8 + j];
                atomicAdd(&accw[lr * ASTR + 2 * j],     bf_lo(w));
                atomicAdd(&accw[lr * ASTR + 2 * j + 1], bf_hi(w));
            }
        }
    }
    __syncthreads();
    // epilogue: 256 threads -> 32 rows x 8 col-pairs
    int rr = t >> 3, jj = t & 7;
    int v = vb + rr;
    if (v < n) {
        float dv = dinv[v];
        float a0 = acc[rr * ASTR + 2 * jj], a1 = acc[rr * ASTR + 2 * jj + 1];
        float bx = bias[s * 16 + 2 * jj], by = bias[s * 16 + 2 * jj + 1];
        float ox = fmaf(dv, a0, bx), oy = fmaf(dv, a1, by);
        if (mode) {  // hidden: relu + bf16 slice-major [8][n][16]
            ox = fmaxf(ox, 0.f); oy = fmaxf(oy, 0.f);
            ((unsigned*)outp)[((size_t)s * n + v) * 8 + jj] = bf16pair(ox, oy);
        } else {     // final fp32 row-major [n][128]
            ((float2*)outp)[(size_t)v * 64 + s * 8 + jj] = make_float2(ox, oy);
        }
    }
}

extern "C" void kernel_launch(void* const* d_in, const int* in_sizes, int n_in,
                              void* d_out, int out_size, void* d_ws, size_t ws_size,
                              hipStream_t stream) {
    const float*    x  = (const float*)d_in[0];
    const float*    W1 = (const float*)d_in[1];
    const float*    b1 = (const float*)d_in[2];
    const float*    W2 = (const float*)d_in[3];
    const float*    b2 = (const float*)d_in[4];
    const unsigned* ei = (const unsigned*)d_in[5];
    int n = in_sizes[0] / 128;
    int E = in_sizes[5] / 2;
    float* out = (float*)d_out;
    int NB = (n + RANGE - 1) >> RB;

    char* w = (char*)d_ws;
    size_t off = 0;
    auto alloc = [&](size_t bytes) -> void* {
        void* p = w + off;
        off = (off + bytes + 255) & ~(size_t)255;
        return p;
    };
    int*            flag     = (int*)alloc(4);
    unsigned*       deg      = (unsigned*)alloc((size_t)n * 4);
    float*          dinv     = (float*)alloc((size_t)n * 4);
    int*            row_off  = (int*)alloc((size_t)(n + 1) * 4);
    unsigned*       gcur     = (unsigned*)alloc(512 * 4);
    uint4*          Bhi1     = (uint4*)alloc(2048 * 16);
    uint4*          Blo1     = (uint4*)alloc(2048 * 16);
    uint4*          Bhi2     = (uint4*)alloc(2048 * 16);
    uint4*          Blo2     = (uint4*)alloc(2048 * 16);
    unsigned*       recs     = (unsigned*)alloc((size_t)NB * CAPB * 4);
    unsigned*       csr      = (unsigned*)alloc((size_t)(E + n + 64) * 4);
    unsigned short* m_bf     = (unsigned short*)alloc((size_t)(n + 1) * 128 * 2);
    unsigned*       h_bf     = (unsigned*)alloc((size_t)n * 64 * 4);
    (void)ws_size; (void)n_in; (void)out_size;

    int nchunk = (E + CHUNK - 1) / CHUNK;
    int mstride = n + 1;

    hipLaunchKernelGGL(setup, dim3(20), dim3(256), 0, stream,
                       ei, E, flag, gcur, NB, W1, Bhi1, Blo1, W2, Bhi2, Blo2,
                       (unsigned*)m_bf, n, mstride);
    hipLaunchKernelGGL(bucketA, dim3(nchunk), dim3(256), 0, stream, ei, E, n, flag, gcur, recs);
    hipLaunchKernelGGL(bucket_deg, dim3(NB), dim3(256), 0, stream, gcur, recs, deg, dinv, n);
    hipLaunchKernelGGL(scan_all, dim3(1), dim3(1024), 0, stream, deg, row_off, n);
    hipLaunchKernelGGL(bucket_csr, dim3(NB), dim3(256), 0, stream, gcur, recs, row_off, csr, n);

    int gblocks = (n + 63) / 64;
    int ablocks = 8 * ((n + 31) / 32);
    // layer 1: m = dinv*(x@W1) ; h = bf16(relu(agg(m) + b1))  [slice-major]
    hipLaunchKernelGGL((gemm_mfma<1>), dim3(gblocks), dim3(256), 0, stream,
                       (const void*)x, 0, Bhi1, Blo1, dinv, m_bf, mstride, n);
    hipLaunchKernelGGL(agg_slice, dim3(ablocks), dim3(256), 0, stream,
                       (const unsigned*)m_bf, csr, row_off, dinv, b1, (void*)h_bf, n, mstride, 1);
    // layer 2: m = dinv*(h@W2) ; out = agg(m) + b2
    hipLaunchKernelGGL((gemm_mfma<0>), dim3(gblocks), dim3(256), 0, stream,
                       (const void*)h_bf, n, Bhi2, Blo2, dinv, m_bf, mstride, n);
    hipLaunchKernelGGL(agg_slice, dim3(ablocks), dim3(256), 0, stream,
                       (const unsigned*)m_bf, csr, row_off, dinv, b2, (void*)out, n, mstride, 0);
}

// Round 8
// 426.009 us; speedup vs baseline: 7.3967x; 7.3967x over previous
//
#include <hip/hip_runtime.h>

// ---------------------------------------------------------------------------
// 2-layer GCN forward:  out = A_norm * relu(A_norm * (x@W1) + b1) @ W2 + b2
// A_norm = D^-1/2 (A+I) D^-1/2, applied as dinv[dst] * sum( dinv[src]*m[src] )
// m bf16 row-major [n][128], dinv[src] pre-folded (halves gather traffic).
// agg (R4-proven): wave = 1 dst row, 64-lane coalesced 256B gathers, 16-deep
// MLP, csr broadcast via shfl. CSR built with 512-node buckets (no write amp).
// GEMMs on MFMA split-bf16 (hi+lo) for fp32-level accuracy.
// ---------------------------------------------------------------------------

#define RB    9
#define RANGE 512
#define CAPB  16384
#define CHUNK 8192

typedef __attribute__((ext_vector_type(8))) short bf16x8;
typedef __attribute__((ext_vector_type(4))) float f32x4;

__device__ inline float bf_lo(unsigned w) { return __uint_as_float(w << 16); }
__device__ inline float bf_hi(unsigned w) { return __uint_as_float(w & 0xffff0000u); }
__device__ inline unsigned bf16pair(float lo, float hi) {  // RNE pack
    unsigned a = __float_as_uint(lo), b = __float_as_uint(hi);
    a += 0x7fffu + ((a >> 16) & 1u);
    b += 0x7fffu + ((b >> 16) & 1u);
    return (a >> 16) | (b & 0xffff0000u);
}
__device__ inline unsigned short bf16rne(float f) {
    unsigned u = __float_as_uint(f);
    u += 0x7fffu + ((u >> 16) & 1u);
    return (unsigned short)(u >> 16);
}
__device__ inline float bf2f(unsigned short h) { return __uint_as_float(((unsigned)h) << 16); }

__device__ inline void pack_one(int idx, const float* __restrict__ W,
                                uint4* __restrict__ Bhi, uint4* __restrict__ Blo) {
    int lane = idx & 63, ks = (idx >> 6) & 3, nt = idx >> 8;
    int j = nt * 16 + (lane & 15);
    int k0 = ks * 32 + ((lane >> 4) & 3) * 8;
    unsigned hi[4], lo[4];
#pragma unroll
    for (int p = 0; p < 4; p++) {
        float w0 = W[(size_t)(k0 + 2 * p) * 128 + j];
        float w1 = W[(size_t)(k0 + 2 * p + 1) * 128 + j];
        unsigned short h0 = bf16rne(w0), h1 = bf16rne(w1);
        unsigned short l0 = bf16rne(w0 - bf2f(h0)), l1 = bf16rne(w1 - bf2f(h1));
        hi[p] = (unsigned)h0 | ((unsigned)h1 << 16);
        lo[p] = (unsigned)l0 | ((unsigned)l1 << 16);
    }
    Bhi[idx] = make_uint4(hi[0], hi[1], hi[2], hi[3]);
    Blo[idx] = make_uint4(lo[0], lo[1], lo[2], lo[3]);
}

// --- fused setup: detect dtype | init gcur | pack W1,W2 --------------------
__global__ __launch_bounds__(256) void setup(const unsigned* __restrict__ ei, int E,
                                             int* __restrict__ flag,
                                             unsigned* __restrict__ gcur, int NB,
                                             const float* __restrict__ W1,
                                             uint4* __restrict__ Bhi1, uint4* __restrict__ Blo1,
                                             const float* __restrict__ W2,
                                             uint4* __restrict__ Bhi2, uint4* __restrict__ Blo2) {
    const int b = blockIdx.x, t = threadIdx.x;
    if (b == 0) {
        __shared__ int nz;
        if (t == 0) nz = 0;
        __syncthreads();
        int samples = E < 2048 ? E : 2048;
        int cnt = 0;
        for (int i = t; i < samples; i += 256)
            if (ei[2 * i + 1] != 0u) cnt++;
        if (cnt) atomicAdd(&nz, cnt);
        __syncthreads();
        if (t == 0) *flag = (nz == 0) ? 1 : 0;  // all high words zero -> int64
    } else if (b <= 2) {
        int i = (b - 1) * 256 + t;
        if (i < NB) gcur[i] = (unsigned)i * CAPB;
    } else if (b <= 10) {
        pack_one((b - 3) * 256 + t, W1, Bhi1, Blo1);
    } else {
        pack_one((b - 11) * 256 + t, W2, Bhi2, Blo2);
    }
}

// --- phase A: edges -> per-bucket record arrays (4B records) ---------------
__global__ __launch_bounds__(256) void bucketA(const unsigned* __restrict__ ei, int E, int n,
                                               const int* __restrict__ flag,
                                               unsigned* __restrict__ gcur,
                                               unsigned* __restrict__ recs) {
    __shared__ unsigned hist[512];
    __shared__ unsigned offs[512];
    const int t = threadIdx.x;
    const int NB = (n + RANGE - 1) >> RB;
    for (int i = t; i < NB; i += 256) hist[i] = 0u;
    __syncthreads();
    const int base = blockIdx.x * CHUNK;
    const bool i64 = (*flag != 0);
    unsigned rec[32], bk[32];
#pragma unroll
    for (int j = 0; j < 32; j++) {
        int i = base + j * 256 + t;
        unsigned bv = 0xffffffffu, rv = 0u;
        if (i < E) {
            unsigned s, d;
            if (i64) { s = ei[2 * (size_t)i]; d = ei[2 * ((size_t)E + i)]; }
            else     { s = ei[i];             d = ei[(size_t)E + i]; }
            bv = d >> RB;
            rv = (s << RB) | (d & (RANGE - 1));
            atomicAdd(&hist[bv], 1u);
        }
        rec[j] = rv; bk[j] = bv;
    }
    __syncthreads();
    for (int b = t; b < NB; b += 256) {
        unsigned h = hist[b];
        offs[b] = h ? atomicAdd(&gcur[b], h) : 0u;
    }
    __syncthreads();
#pragma unroll
    for (int j = 0; j < 32; j++) {
        unsigned b = bk[j];
        if (b != 0xffffffffu) {
            unsigned pos = atomicAdd(&offs[b], 1u);
            if (pos < (b + 1u) * CAPB) recs[pos] = rec[j];
        }
    }
}

// --- phase A2: per-bucket degree + dinv (self-loop included) ---------------
__global__ __launch_bounds__(256) void bucket_deg(const unsigned* __restrict__ gcur,
                                                  const unsigned* __restrict__ recs,
                                                  unsigned* __restrict__ deg,
                                                  float* __restrict__ dinv, int n) {
    __shared__ unsigned dl[RANGE];
    const int b = blockIdx.x, t = threadIdx.x;
    const int node0 = b << RB;
    for (int v = t; v < RANGE; v += 256) dl[v] = 1u;
    __syncthreads();
    unsigned base = (unsigned)b * CAPB;
    unsigned cnt = gcur[b] - base; if (cnt > CAPB) cnt = CAPB;
    for (unsigned i = t; i < cnt; i += 256)
        atomicAdd(&dl[recs[base + i] & (RANGE - 1)], 1u);
    __syncthreads();
    for (int v = t; v < RANGE; v += 256)
        if (node0 + v < n) {
            unsigned d = dl[v];
            deg[node0 + v] = d;
            dinv[node0 + v] = rsqrtf((float)d);
        }
}

// --- single-block exclusive scan: deg[n] -> row_off[n+1] -------------------
__global__ __launch_bounds__(1024) void scan_all(const unsigned* __restrict__ deg,
                                                 int* __restrict__ row_off, int n) {
    __shared__ unsigned wsum[16];
    const int t = threadIdx.x;
    const int K = (n + 1023) >> 10;
    const int base = t * K;
    unsigned s = 0;
    for (int k = 0; k < K; k++) {
        int i = base + k;
        if (i < n) s += deg[i];
    }
    const int lane = t & 63, wv = t >> 6;
    unsigned inc = s;
    for (int o = 1; o < 64; o <<= 1) {
        unsigned u = (unsigned)__shfl_up((int)inc, o, 64);
        if (lane >= o) inc += u;
    }
    if (lane == 63) wsum[wv] = inc;
    __syncthreads();
    if (t < 16) {
        unsigned v = wsum[t];
        unsigned in2 = v;
        for (int o = 1; o < 16; o <<= 1) {
            unsigned u = (unsigned)__shfl_up((int)in2, o, 64);
            if (t >= o) in2 += u;
        }
        wsum[t] = in2 - v;  // exclusive
    }
    __syncthreads();
    unsigned excl = wsum[wv] + inc - s;
    for (int k = 0; k < K; k++) {
        int i = base + k;
        if (i < n) { unsigned d = deg[i]; row_off[i] = (int)excl; excl += d; }
    }
    if (t == 1023) row_off[n] = (int)excl;
}

// --- phase B: per-bucket CSR scatter ---------------------------------------
__global__ __launch_bounds__(256) void bucket_csr(const unsigned* __restrict__ gcur,
                                                  const unsigned* __restrict__ recs,
                                                  const int* __restrict__ row_off,
                                                  int* __restrict__ csr, int n) {
    __shared__ int cur[RANGE];
    const int b = blockIdx.x, t = threadIdx.x;
    const int node0 = b << RB;
    for (int v = t; v < RANGE; v += 256) {
        int node = node0 + v;
        if (node < n) {
            int ro = row_off[node];
            csr[ro] = node;      // self-loop entry
            cur[v] = ro + 1;
        }
    }
    __syncthreads();
    unsigned base = (unsigned)b * CAPB;
    unsigned cnt = gcur[b] - base; if (cnt > CAPB) cnt = CAPB;
    for (unsigned i = t; i < cnt; i += 256) {
        unsigned r = recs[base + i];
        int pos = atomicAdd(&cur[r & (RANGE - 1)], 1);
        csr[pos] = (int)(r >> RB);
    }
}

// --- MFMA GEMM: Mout[M,128](bf16 row-major) = dinv[r] * (A[M,128] @ W) ------
// SPLIT=1: A fp32 row-major (3 mfma terms). SPLIT=0: A bf16 row-major (2).
template <int SPLIT>
__global__ __launch_bounds__(256) void gemm_mfma(const void* __restrict__ Ain,
                                                 const uint4* __restrict__ Bhi,
                                                 const uint4* __restrict__ Blo,
                                                 const float* __restrict__ dinv,
                                                 unsigned short* __restrict__ Mout, int M) {
    __shared__ unsigned short Ahi[64 * 128];
    __shared__ unsigned short Alo[SPLIT ? 64 * 128 : 64];
    const int t = threadIdx.x;
    const int row0 = blockIdx.x * 64;
    char* ah8 = (char*)Ahi;
    char* al8 = (char*)Alo;

    if (SPLIT) {
        const float4* A4 = (const float4*)Ain;
#pragma unroll
        for (int it = 0; it < 4; it++) {
            int i = it * 256 + t;
            int r = i >> 4, c8 = i & 15;
            int gr = row0 + r;
            float4 v0 = make_float4(0.f, 0.f, 0.f, 0.f), v1 = v0;
            if (gr < M) { v0 = A4[(size_t)gr * 32 + c8 * 2]; v1 = A4[(size_t)gr * 32 + c8 * 2 + 1]; }
            float f[8] = {v0.x, v0.y, v0.z, v0.w, v1.x, v1.y, v1.z, v1.w};
            unsigned hp[4], lp[4];
#pragma unroll
            for (int p = 0; p < 4; p++) {
                unsigned short h0 = bf16rne(f[2 * p]), h1 = bf16rne(f[2 * p + 1]);
                unsigned short l0 = bf16rne(f[2 * p] - bf2f(h0));
                unsigned short l1 = bf16rne(f[2 * p + 1] - bf2f(h1));
                hp[p] = (unsigned)h0 | ((unsigned)h1 << 16);
                lp[p] = (unsigned)l0 | ((unsigned)l1 << 16);
            }
            int byte = (r * 256 + c8 * 16) ^ ((r & 7) << 4);
            *(uint4*)(ah8 + byte) = make_uint4(hp[0], hp[1], hp[2], hp[3]);
            *(uint4*)(al8 + byte) = make_uint4(lp[0], lp[1], lp[2], lp[3]);
        }
    } else {
        const uint4* A4 = (const uint4*)Ain;
#pragma unroll
        for (int it = 0; it < 4; it++) {
            int i = it * 256 + t;
            int r = i >> 4, c8 = i & 15;
            int gr = row0 + r;
            uint4 v = make_uint4(0u, 0u, 0u, 0u);
            if (gr < M) v = A4[(size_t)gr * 16 + c8];
            int byte = (r * 256 + c8 * 16) ^ ((r & 7) << 4);
            *(uint4*)(ah8 + byte) = v;
        }
    }
    __syncthreads();

    const int wv = t >> 6, lane = t & 63;
    const int arow = wv * 16 + (lane & 15);
    const int kh = ((lane >> 4) & 3) * 8;
    f32x4 acc[8];
#pragma unroll
    for (int nt = 0; nt < 8; nt++) acc[nt] = (f32x4){0.f, 0.f, 0.f, 0.f};
    float dv[4];
    const int orow0 = row0 + wv * 16 + ((lane >> 4) & 3) * 4;
#pragma unroll
    for (int r = 0; r < 4; r++) {
        int rr = orow0 + r;
        dv[r] = (rr < M) ? dinv[rr] : 0.f;
    }
#pragma unroll
    for (int ks = 0; ks < 4; ks++) {
        int byte = (arow * 256 + (ks * 32 + kh) * 2) ^ ((arow & 7) << 4);
        bf16x8 a_h = *(const bf16x8*)(ah8 + byte);
        bf16x8 a_l;
        if (SPLIT) a_l = *(const bf16x8*)(al8 + byte);
#pragma unroll
        for (int nt = 0; nt < 8; nt++) {
            uint4 bhv = Bhi[(nt * 4 + ks) * 64 + lane];
            uint4 blv = Blo[(nt * 4 + ks) * 64 + lane];
            bf16x8 bh = *(bf16x8*)&bhv;
            bf16x8 bl = *(bf16x8*)&blv;
            acc[nt] = __builtin_amdgcn_mfma_f32_16x16x32_bf16(a_h, bh, acc[nt], 0, 0, 0);
            if (SPLIT) acc[nt] = __builtin_amdgcn_mfma_f32_16x16x32_bf16(a_l, bh, acc[nt], 0, 0, 0);
            acc[nt] = __builtin_amdgcn_mfma_f32_16x16x32_bf16(a_h, bl, acc[nt], 0, 0, 0);
        }
    }
    __syncthreads();
    // epilogue: acc -> (bf16 * dinv) via LDS transpose -> coalesced stores
#pragma unroll
    for (int nt = 0; nt < 8; nt++) {
#pragma unroll
        for (int r = 0; r < 4; r++) {
            int lr = wv * 16 + ((lane >> 4) & 3) * 4 + r;
            int byte = (lr * 256 + (nt * 16 + (lane & 15)) * 2) ^ ((lr & 7) << 4);
            *(unsigned short*)(ah8 + byte) = bf16rne(acc[nt][r] * dv[r]);
        }
    }
    __syncthreads();
#pragma unroll
    for (int it = 0; it < 4; it++) {
        int i = it * 256 + t;
        int r = i >> 4, c8 = i & 15;
        int gr = row0 + r;
        if (gr < M) {
            int byte = (r * 256 + c8 * 16) ^ ((r & 7) << 4);
            *(uint4*)(Mout + (size_t)gr * 128 + c8 * 8) = *(uint4*)(ah8 + byte);
        }
    }
}

// --- aggregation (R4-proven): out[v] = dinv[v]*sum_{e} m'[src_e] + b -------
__global__ __launch_bounds__(256) void agg_kernel(const unsigned* __restrict__ m,
                                                  const int* __restrict__ csr,
                                                  const int* __restrict__ row_off,
                                                  const unsigned* __restrict__ deg,
                                                  const float* __restrict__ dinv,
                                                  const float* __restrict__ bias,
                                                  void* __restrict__ outp, int n, int mode) {
    int wid = threadIdx.x >> 6, lane = threadIdx.x & 63;
    int v = blockIdx.x * 4 + wid;
    if (v >= n) return;
    int start = row_off[v];
    int cnt = (int)deg[v];
    float ax = 0.f, ay = 0.f;
    int e = 0;
    while (e < cnt) {
        int nload = cnt - e;
        if (nload > 64) nload = 64;
        int sv = 0;
        if (lane < nload) sv = csr[start + e + lane];
        int j = 0;
        for (; j + 16 <= nload; j += 16) {
            unsigned w[16];
#pragma unroll
            for (int q = 0; q < 16; q++) {
                int s = __shfl(sv, j + q);
                w[q] = m[(size_t)s * 64 + lane];
            }
#pragma unroll
            for (int q = 0; q < 16; q++) { ax += bf_lo(w[q]); ay += bf_hi(w[q]); }
        }
        if (j + 8 <= nload) {
            unsigned w[8];
#pragma unroll
            for (int q = 0; q < 8; q++) {
                int s = __shfl(sv, j + q);
                w[q] = m[(size_t)s * 64 + lane];
            }
#pragma unroll
            for (int q = 0; q < 8; q++) { ax += bf_lo(w[q]); ay += bf_hi(w[q]); }
            j += 8;
        }
        for (; j < nload; j++) {
            int s = __shfl(sv, j);
            unsigned w = m[(size_t)s * 64 + lane];
            ax += bf_lo(w); ay += bf_hi(w);
        }
        e += nload;
    }
    float dv = dinv[v];
    float2 b = ((const float2*)bias)[lane];
    float ox = fmaf(dv, ax, b.x), oy = fmaf(dv, ay, b.y);
    if (mode) {
        ox = fmaxf(ox, 0.f); oy = fmaxf(oy, 0.f);
        ((unsigned*)outp)[(size_t)v * 64 + lane] = bf16pair(ox, oy);
    } else {
        ((float2*)outp)[(size_t)v * 64 + lane] = make_float2(ox, oy);
    }
}

extern "C" void kernel_launch(void* const* d_in, const int* in_sizes, int n_in,
                              void* d_out, int out_size, void* d_ws, size_t ws_size,
                              hipStream_t stream) {
    const float*    x  = (const float*)d_in[0];
    const float*    W1 = (const float*)d_in[1];
    const float*    b1 = (const float*)d_in[2];
    const float*    W2 = (const float*)d_in[3];
    const float*    b2 = (const float*)d_in[4];
    const unsigned* ei = (const unsigned*)d_in[5];
    int n = in_sizes[0] / 128;
    int E = in_sizes[5] / 2;
    float* out = (float*)d_out;
    int NB = (n + RANGE - 1) >> RB;

    char* w = (char*)d_ws;
    size_t off = 0;
    auto alloc = [&](size_t bytes) -> void* {
        void* p = w + off;
        off = (off + bytes + 255) & ~(size_t)255;
        return p;
    };
    int*            flag     = (int*)alloc(4);
    unsigned*       deg      = (unsigned*)alloc((size_t)n * 4);
    float*          dinv     = (float*)alloc((size_t)n * 4);
    int*            row_off  = (int*)alloc((size_t)(n + 1) * 4);
    unsigned*       gcur     = (unsigned*)alloc(512 * 4);
    uint4*          Bhi1     = (uint4*)alloc(2048 * 16);
    uint4*          Blo1     = (uint4*)alloc(2048 * 16);
    uint4*          Bhi2     = (uint4*)alloc(2048 * 16);
    uint4*          Blo2     = (uint4*)alloc(2048 * 16);
    unsigned*       recs     = (unsigned*)alloc((size_t)NB * CAPB * 4);
    int*            csr      = (int*)alloc((size_t)(E + n + 64) * 4);
    unsigned short* m_bf     = (unsigned short*)alloc((size_t)n * 128 * 2);
    unsigned*       h_bf     = (unsigned*)alloc((size_t)n * 64 * 4);
    (void)ws_size; (void)n_in; (void)out_size;

    int nchunk = (E + CHUNK - 1) / CHUNK;

    hipLaunchKernelGGL(setup, dim3(19), dim3(256), 0, stream,
                       ei, E, flag, gcur, NB, W1, Bhi1, Blo1, W2, Bhi2, Blo2);
    hipLaunchKernelGGL(bucketA, dim3(nchunk), dim3(256), 0, stream, ei, E, n, flag, gcur, recs);
    hipLaunchKernelGGL(bucket_deg, dim3(NB), dim3(256), 0, stream, gcur, recs, deg, dinv, n);
    hipLaunchKernelGGL(scan_all, dim3(1), dim3(1024), 0, stream, deg, row_off, n);
    hipLaunchKernelGGL(bucket_csr, dim3(NB), dim3(256), 0, stream, gcur, recs, row_off, csr, n);

    int gblocks = (n + 63) / 64;
    // layer 1: m = dinv*(x@W1) ; h = bf16(relu(agg(m) + b1))
    hipLaunchKernelGGL((gemm_mfma<1>), dim3(gblocks), dim3(256), 0, stream,
                       (const void*)x, Bhi1, Blo1, dinv, m_bf, n);
    hipLaunchKernelGGL(agg_kernel, dim3((n + 3) / 4), dim3(256), 0, stream,
                       (const unsigned*)m_bf, csr, row_off, deg, dinv, b1, (void*)h_bf, n, 1);
    // layer 2: m = dinv*(h@W2) ; out = agg(m) + b2
    hipLaunchKernelGGL((gemm_mfma<0>), dim3(gblocks), dim3(256), 0, stream,
                       (const void*)h_bf, Bhi2, Blo2, dinv, m_bf, n);
    hipLaunchKernelGGL(agg_kernel, dim3((n + 3) / 4), dim3(256), 0, stream,
                       (const unsigned*)m_bf, csr, row_off, deg, dinv, b2, (void*)out, n, 0);
}

// Round 9
// 246.994 us; speedup vs baseline: 12.7577x; 1.7248x over previous
//
#include <hip/hip_runtime.h>

// ---------------------------------------------------------------------------
// 2-layer GCN forward:  out = A_norm * relu(A_norm * (x@W1) + b1) @ W2 + b2
// A_norm = D^-1/2 (A+I) D^-1/2, applied as dinv[dst] * sum( dinv[src]*m[src] )
// m bf16 row-major [n][128], dinv[src] pre-folded (halves gather traffic).
// agg (R4-proven): wave = 1 dst row, 64-lane coalesced 256B gathers, 16-deep
// MLP, csr broadcast via shfl. CSR built with 512-node buckets (no write amp).
// Scan: proven 3-kernel multi-block version (R8's single-block scan was 193us).
// GEMMs on MFMA split-bf16 (hi+lo) for fp32-level accuracy.
// ---------------------------------------------------------------------------

#define RB    9
#define RANGE 512
#define CAPB  16384
#define CHUNK 8192

typedef __attribute__((ext_vector_type(8))) short bf16x8;
typedef __attribute__((ext_vector_type(4))) float f32x4;

__device__ inline float bf_lo(unsigned w) { return __uint_as_float(w << 16); }
__device__ inline float bf_hi(unsigned w) { return __uint_as_float(w & 0xffff0000u); }
__device__ inline unsigned bf16pair(float lo, float hi) {  // RNE pack
    unsigned a = __float_as_uint(lo), b = __float_as_uint(hi);
    a += 0x7fffu + ((a >> 16) & 1u);
    b += 0x7fffu + ((b >> 16) & 1u);
    return (a >> 16) | (b & 0xffff0000u);
}
__device__ inline unsigned short bf16rne(float f) {
    unsigned u = __float_as_uint(f);
    u += 0x7fffu + ((u >> 16) & 1u);
    return (unsigned short)(u >> 16);
}
__device__ inline float bf2f(unsigned short h) { return __uint_as_float(((unsigned)h) << 16); }

__device__ inline void pack_one(int idx, const float* __restrict__ W,
                                uint4* __restrict__ Bhi, uint4* __restrict__ Blo) {
    int lane = idx & 63, ks = (idx >> 6) & 3, nt = idx >> 8;
    int j = nt * 16 + (lane & 15);
    int k0 = ks * 32 + ((lane >> 4) & 3) * 8;
    unsigned hi[4], lo[4];
#pragma unroll
    for (int p = 0; p < 4; p++) {
        float w0 = W[(size_t)(k0 + 2 * p) * 128 + j];
        float w1 = W[(size_t)(k0 + 2 * p + 1) * 128 + j];
        unsigned short h0 = bf16rne(w0), h1 = bf16rne(w1);
        unsigned short l0 = bf16rne(w0 - bf2f(h0)), l1 = bf16rne(w1 - bf2f(h1));
        hi[p] = (unsigned)h0 | ((unsigned)h1 << 16);
        lo[p] = (unsigned)l0 | ((unsigned)l1 << 16);
    }
    Bhi[idx] = make_uint4(hi[0], hi[1], hi[2], hi[3]);
    Blo[idx] = make_uint4(lo[0], lo[1], lo[2], lo[3]);
}

// --- fused setup: detect dtype | init gcur | pack W1,W2 --------------------
__global__ __launch_bounds__(256) void setup(const unsigned* __restrict__ ei, int E,
                                             int* __restrict__ flag,
                                             unsigned* __restrict__ gcur, int NB,
                                             const float* __restrict__ W1,
                                             uint4* __restrict__ Bhi1, uint4* __restrict__ Blo1,
                                             const float* __restrict__ W2,
                                             uint4* __restrict__ Bhi2, uint4* __restrict__ Blo2) {
    const int b = blockIdx.x, t = threadIdx.x;
    if (b == 0) {
        __shared__ int nz;
        if (t == 0) nz = 0;
        __syncthreads();
        int samples = E < 2048 ? E : 2048;
        int cnt = 0;
        for (int i = t; i < samples; i += 256)
            if (ei[2 * i + 1] != 0u) cnt++;
        if (cnt) atomicAdd(&nz, cnt);
        __syncthreads();
        if (t == 0) *flag = (nz == 0) ? 1 : 0;  // all high words zero -> int64
    } else if (b <= 2) {
        int i = (b - 1) * 256 + t;
        if (i < NB) gcur[i] = (unsigned)i * CAPB;
    } else if (b <= 10) {
        pack_one((b - 3) * 256 + t, W1, Bhi1, Blo1);
    } else {
        pack_one((b - 11) * 256 + t, W2, Bhi2, Blo2);
    }
}

// --- phase A: edges -> per-bucket record arrays (4B records) ---------------
__global__ __launch_bounds__(256) void bucketA(const unsigned* __restrict__ ei, int E, int n,
                                               const int* __restrict__ flag,
                                               unsigned* __restrict__ gcur,
                                               unsigned* __restrict__ recs) {
    __shared__ unsigned hist[512];
    __shared__ unsigned offs[512];
    const int t = threadIdx.x;
    const int NB = (n + RANGE - 1) >> RB;
    for (int i = t; i < NB; i += 256) hist[i] = 0u;
    __syncthreads();
    const int base = blockIdx.x * CHUNK;
    const bool i64 = (*flag != 0);
    unsigned rec[32], bk[32];
#pragma unroll
    for (int j = 0; j < 32; j++) {
        int i = base + j * 256 + t;
        unsigned bv = 0xffffffffu, rv = 0u;
        if (i < E) {
            unsigned s, d;
            if (i64) { s = ei[2 * (size_t)i]; d = ei[2 * ((size_t)E + i)]; }
            else     { s = ei[i];             d = ei[(size_t)E + i]; }
            bv = d >> RB;
            rv = (s << RB) | (d & (RANGE - 1));
            atomicAdd(&hist[bv], 1u);
        }
        rec[j] = rv; bk[j] = bv;
    }
    __syncthreads();
    for (int b = t; b < NB; b += 256) {
        unsigned h = hist[b];
        offs[b] = h ? atomicAdd(&gcur[b], h) : 0u;
    }
    __syncthreads();
#pragma unroll
    for (int j = 0; j < 32; j++) {
        unsigned b = bk[j];
        if (b != 0xffffffffu) {
            unsigned pos = atomicAdd(&offs[b], 1u);
            if (pos < (b + 1u) * CAPB) recs[pos] = rec[j];
        }
    }
}

// --- phase A2: per-bucket degree + dinv (self-loop included) ---------------
__global__ __launch_bounds__(256) void bucket_deg(const unsigned* __restrict__ gcur,
                                                  const unsigned* __restrict__ recs,
                                                  unsigned* __restrict__ deg,
                                                  float* __restrict__ dinv, int n) {
    __shared__ unsigned dl[RANGE];
    const int b = blockIdx.x, t = threadIdx.x;
    const int node0 = b << RB;
    for (int v = t; v < RANGE; v += 256) dl[v] = 1u;
    __syncthreads();
    unsigned base = (unsigned)b * CAPB;
    unsigned cnt = gcur[b] - base; if (cnt > CAPB) cnt = CAPB;
    for (unsigned i = t; i < cnt; i += 256)
        atomicAdd(&dl[recs[base + i] & (RANGE - 1)], 1u);
    __syncthreads();
    for (int v = t; v < RANGE; v += 256)
        if (node0 + v < n) {
            unsigned d = dl[v];
            deg[node0 + v] = d;
            dinv[node0 + v] = rsqrtf((float)d);
        }
}

// --- 3-kernel exclusive scan of deg -> row_off (proven, coalesced) ---------
__global__ void scan_block_sums(const unsigned* deg, unsigned* partials, int n) {
    __shared__ unsigned sdata[256];
    int b = blockIdx.x, t = threadIdx.x;
    int base = b * 1024;
    unsigned s = 0;
    for (int j = 0; j < 4; j++) {
        int i = base + t * 4 + j;
        if (i < n) s += deg[i];
    }
    sdata[t] = s;
    __syncthreads();
    for (int stride = 128; stride > 0; stride >>= 1) {
        if (t < stride) sdata[t] += sdata[t + stride];
        __syncthreads();
    }
    if (t == 0) partials[b] = sdata[0];
}

__global__ void scan_partials(unsigned* partials, int nb) {
    int lane = threadIdx.x;  // one wave (64)
    int K = (nb + 63) / 64;
    if (K > 8) K = 8;
    unsigned vals[8];
    unsigned s = 0;
#pragma unroll
    for (int k = 0; k < 8; k++) {
        int i = lane * K + k;
        vals[k] = (k < K && i < nb) ? partials[i] : 0u;
        s += vals[k];
    }
    unsigned inc = s;
    for (int o = 1; o < 64; o <<= 1) {
        unsigned u = (unsigned)__shfl_up((int)inc, o, 64);
        if (lane >= o) inc += u;
    }
    unsigned excl = inc - s;
#pragma unroll
    for (int k = 0; k < 8; k++) {
        int i = lane * K + k;
        if (k < K && i < nb) { unsigned t = vals[k]; partials[i] = excl; excl += t; }
    }
}

__global__ void scan_write(const unsigned* deg, const unsigned* partials,
                           int* row_off, int n) {
    int b = blockIdx.x, t = threadIdx.x;
    int lane = t & 63, wid = t >> 6;
    int base = b * 1024;
    unsigned vals[4];
    unsigned s = 0;
    for (int j = 0; j < 4; j++) {
        int i = base + t * 4 + j;
        vals[j] = (i < n) ? deg[i] : 0u;
        s += vals[j];
    }
    unsigned inc = s;
    for (int o = 1; o < 64; o <<= 1) {
        unsigned u = (unsigned)__shfl_up((int)inc, o, 64);
        if (lane >= o) inc += u;
    }
    __shared__ unsigned wtot[4];
    if (lane == 63) wtot[wid] = inc;
    __syncthreads();
    unsigned wbase = 0;
    for (int w = 0; w < wid; w++) wbase += wtot[w];
    unsigned excl = partials[b] + wbase + (inc - s);
    for (int j = 0; j < 4; j++) {
        int i = base + t * 4 + j;
        if (i < n) { row_off[i] = (int)excl; excl += vals[j]; }
    }
}

// --- phase B: per-bucket CSR scatter ---------------------------------------
__global__ __launch_bounds__(256) void bucket_csr(const unsigned* __restrict__ gcur,
                                                  const unsigned* __restrict__ recs,
                                                  const int* __restrict__ row_off,
                                                  int* __restrict__ csr, int n) {
    __shared__ int cur[RANGE];
    const int b = blockIdx.x, t = threadIdx.x;
    const int node0 = b << RB;
    for (int v = t; v < RANGE; v += 256) {
        int node = node0 + v;
        if (node < n) {
            int ro = row_off[node];
            csr[ro] = node;      // self-loop entry
            cur[v] = ro + 1;
        }
    }
    __syncthreads();
    unsigned base = (unsigned)b * CAPB;
    unsigned cnt = gcur[b] - base; if (cnt > CAPB) cnt = CAPB;
    for (unsigned i = t; i < cnt; i += 256) {
        unsigned r = recs[base + i];
        int pos = atomicAdd(&cur[r & (RANGE - 1)], 1);
        csr[pos] = (int)(r >> RB);
    }
}

// --- MFMA GEMM: Mout[M,128](bf16 row-major) = dinv[r] * (A[M,128] @ W) ------
// SPLIT=1: A fp32 row-major (3 mfma terms). SPLIT=0: A bf16 row-major (2).
template <int SPLIT>
__global__ __launch_bounds__(256) void gemm_mfma(const void* __restrict__ Ain,
                                                 const uint4* __restrict__ Bhi,
                                                 const uint4* __restrict__ Blo,
                                                 const float* __restrict__ dinv,
                                                 unsigned short* __restrict__ Mout, int M) {
    __shared__ unsigned short Ahi[64 * 128];
    __shared__ unsigned short Alo[SPLIT ? 64 * 128 : 64];
    const int t = threadIdx.x;
    const int row0 = blockIdx.x * 64;
    char* ah8 = (char*)Ahi;
    char* al8 = (char*)Alo;

    if (SPLIT) {
        const float4* A4 = (const float4*)Ain;
#pragma unroll
        for (int it = 0; it < 4; it++) {
            int i = it * 256 + t;
            int r = i >> 4, c8 = i & 15;
            int gr = row0 + r;
            float4 v0 = make_float4(0.f, 0.f, 0.f, 0.f), v1 = v0;
            if (gr < M) { v0 = A4[(size_t)gr * 32 + c8 * 2]; v1 = A4[(size_t)gr * 32 + c8 * 2 + 1]; }
            float f[8] = {v0.x, v0.y, v0.z, v0.w, v1.x, v1.y, v1.z, v1.w};
            unsigned hp[4], lp[4];
#pragma unroll
            for (int p = 0; p < 4; p++) {
                unsigned short h0 = bf16rne(f[2 * p]), h1 = bf16rne(f[2 * p + 1]);
                unsigned short l0 = bf16rne(f[2 * p] - bf2f(h0));
                unsigned short l1 = bf16rne(f[2 * p + 1] - bf2f(h1));
                hp[p] = (unsigned)h0 | ((unsigned)h1 << 16);
                lp[p] = (unsigned)l0 | ((unsigned)l1 << 16);
            }
            int byte = (r * 256 + c8 * 16) ^ ((r & 7) << 4);
            *(uint4*)(ah8 + byte) = make_uint4(hp[0], hp[1], hp[2], hp[3]);
            *(uint4*)(al8 + byte) = make_uint4(lp[0], lp[1], lp[2], lp[3]);
        }
    } else {
        const uint4* A4 = (const uint4*)Ain;
#pragma unroll
        for (int it = 0; it < 4; it++) {
            int i = it * 256 + t;
            int r = i >> 4, c8 = i & 15;
            int gr = row0 + r;
            uint4 v = make_uint4(0u, 0u, 0u, 0u);
            if (gr < M) v = A4[(size_t)gr * 16 + c8];
            int byte = (r * 256 + c8 * 16) ^ ((r & 7) << 4);
            *(uint4*)(ah8 + byte) = v;
        }
    }
    __syncthreads();

    const int wv = t >> 6, lane = t & 63;
    const int arow = wv * 16 + (lane & 15);
    const int kh = ((lane >> 4) & 3) * 8;
    f32x4 acc[8];
#pragma unroll
    for (int nt = 0; nt < 8; nt++) acc[nt] = (f32x4){0.f, 0.f, 0.f, 0.f};
    float dv[4];
    const int orow0 = row0 + wv * 16 + ((lane >> 4) & 3) * 4;
#pragma unroll
    for (int r = 0; r < 4; r++) {
        int rr = orow0 + r;
        dv[r] = (rr < M) ? dinv[rr] : 0.f;
    }
#pragma unroll
    for (int ks = 0; ks < 4; ks++) {
        int byte = (arow * 256 + (ks * 32 + kh) * 2) ^ ((arow & 7) << 4);
        bf16x8 a_h = *(const bf16x8*)(ah8 + byte);
        bf16x8 a_l;
        if (SPLIT) a_l = *(const bf16x8*)(al8 + byte);
#pragma unroll
        for (int nt = 0; nt < 8; nt++) {
            uint4 bhv = Bhi[(nt * 4 + ks) * 64 + lane];
            uint4 blv = Blo[(nt * 4 + ks) * 64 + lane];
            bf16x8 bh = *(bf16x8*)&bhv;
            bf16x8 bl = *(bf16x8*)&blv;
            acc[nt] = __builtin_amdgcn_mfma_f32_16x16x32_bf16(a_h, bh, acc[nt], 0, 0, 0);
            if (SPLIT) acc[nt] = __builtin_amdgcn_mfma_f32_16x16x32_bf16(a_l, bh, acc[nt], 0, 0, 0);
            acc[nt] = __builtin_amdgcn_mfma_f32_16x16x32_bf16(a_h, bl, acc[nt], 0, 0, 0);
        }
    }
    __syncthreads();
    // epilogue: acc -> (bf16 * dinv) via LDS transpose -> coalesced stores
#pragma unroll
    for (int nt = 0; nt < 8; nt++) {
#pragma unroll
        for (int r = 0; r < 4; r++) {
            int lr = wv * 16 + ((lane >> 4) & 3) * 4 + r;
            int byte = (lr * 256 + (nt * 16 + (lane & 15)) * 2) ^ ((lr & 7) << 4);
            *(unsigned short*)(ah8 + byte) = bf16rne(acc[nt][r] * dv[r]);
        }
    }
    __syncthreads();
#pragma unroll
    for (int it = 0; it < 4; it++) {
        int i = it * 256 + t;
        int r = i >> 4, c8 = i & 15;
        int gr = row0 + r;
        if (gr < M) {
            int byte = (r * 256 + c8 * 16) ^ ((r & 7) << 4);
            *(uint4*)(Mout + (size_t)gr * 128 + c8 * 8) = *(uint4*)(ah8 + byte);
        }
    }
}

// --- aggregation (R4-proven): out[v] = dinv[v]*sum_{e} m'[src_e] + b -------
__global__ __launch_bounds__(256) void agg_kernel(const unsigned* __restrict__ m,
                                                  const int* __restrict__ csr,
                                                  const int* __restrict__ row_off,
                                                  const unsigned* __restrict__ deg,
                                                  const float* __restrict__ dinv,
                                                  const float* __restrict__ bias,
                                                  void* __restrict__ outp, int n, int mode) {
    int wid = threadIdx.x >> 6, lane = threadIdx.x & 63;
    int v = blockIdx.x * 4 + wid;
    if (v >= n) return;
    int start = row_off[v];
    int cnt = (int)deg[v];
    float ax = 0.f, ay = 0.f;
    int e = 0;
    while (e < cnt) {
        int nload = cnt - e;
        if (nload > 64) nload = 64;
        int sv = 0;
        if (lane < nload) sv = csr[start + e + lane];
        int j = 0;
        for (; j + 16 <= nload; j += 16) {
            unsigned w[16];
#pragma unroll
            for (int q = 0; q < 16; q++) {
                int s = __shfl(sv, j + q);
                w[q] = m[(size_t)s * 64 + lane];
            }
#pragma unroll
            for (int q = 0; q < 16; q++) { ax += bf_lo(w[q]); ay += bf_hi(w[q]); }
        }
        if (j + 8 <= nload) {
            unsigned w[8];
#pragma unroll
            for (int q = 0; q < 8; q++) {
                int s = __shfl(sv, j + q);
                w[q] = m[(size_t)s * 64 + lane];
            }
#pragma unroll
            for (int q = 0; q < 8; q++) { ax += bf_lo(w[q]); ay += bf_hi(w[q]); }
            j += 8;
        }
        for (; j < nload; j++) {
            int s = __shfl(sv, j);
            unsigned w = m[(size_t)s * 64 + lane];
            ax += bf_lo(w); ay += bf_hi(w);
        }
        e += nload;
    }
    float dv = dinv[v];
    float2 b = ((const float2*)bias)[lane];
    float ox = fmaf(dv, ax, b.x), oy = fmaf(dv, ay, b.y);
    if (mode) {
        ox = fmaxf(ox, 0.f); oy = fmaxf(oy, 0.f);
        ((unsigned*)outp)[(size_t)v * 64 + lane] = bf16pair(ox, oy);
    } else {
        ((float2*)outp)[(size_t)v * 64 + lane] = make_float2(ox, oy);
    }
}

extern "C" void kernel_launch(void* const* d_in, const int* in_sizes, int n_in,
                              void* d_out, int out_size, void* d_ws, size_t ws_size,
                              hipStream_t stream) {
    const float*    x  = (const float*)d_in[0];
    const float*    W1 = (const float*)d_in[1];
    const float*    b1 = (const float*)d_in[2];
    const float*    W2 = (const float*)d_in[3];
    const float*    b2 = (const float*)d_in[4];
    const unsigned* ei = (const unsigned*)d_in[5];
    int n = in_sizes[0] / 128;
    int E = in_sizes[5] / 2;
    float* out = (float*)d_out;
    int NB = (n + RANGE - 1) >> RB;

    char* w = (char*)d_ws;
    size_t off = 0;
    auto alloc = [&](size_t bytes) -> void* {
        void* p = w + off;
        off = (off + bytes + 255) & ~(size_t)255;
        return p;
    };
    int*            flag     = (int*)alloc(4);
    unsigned*       deg      = (unsigned*)alloc((size_t)n * 4);
    float*          dinv     = (float*)alloc((size_t)n * 4);
    int*            row_off  = (int*)alloc((size_t)(n + 1) * 4);
    unsigned*       partials = (unsigned*)alloc(4096 * 4);
    unsigned*       gcur     = (unsigned*)alloc(512 * 4);
    uint4*          Bhi1     = (uint4*)alloc(2048 * 16);
    uint4*          Blo1     = (uint4*)alloc(2048 * 16);
    uint4*          Bhi2     = (uint4*)alloc(2048 * 16);
    uint4*          Blo2     = (uint4*)alloc(2048 * 16);
    unsigned*       recs     = (unsigned*)alloc((size_t)NB * CAPB * 4);
    int*            csr      = (int*)alloc((size_t)(E + n + 64) * 4);
    unsigned short* m_bf     = (unsigned short*)alloc((size_t)n * 128 * 2);
    unsigned*       h_bf     = (unsigned*)alloc((size_t)n * 64 * 4);
    (void)ws_size; (void)n_in; (void)out_size;

    int nchunk = (E + CHUNK - 1) / CHUNK;
    int nb = (n + 1023) / 1024;

    hipLaunchKernelGGL(setup, dim3(19), dim3(256), 0, stream,
                       ei, E, flag, gcur, NB, W1, Bhi1, Blo1, W2, Bhi2, Blo2);
    hipLaunchKernelGGL(bucketA, dim3(nchunk), dim3(256), 0, stream, ei, E, n, flag, gcur, recs);
    hipLaunchKernelGGL(bucket_deg, dim3(NB), dim3(256), 0, stream, gcur, recs, deg, dinv, n);
    hipLaunchKernelGGL(scan_block_sums, dim3(nb), dim3(256), 0, stream, deg, partials, n);
    hipLaunchKernelGGL(scan_partials, dim3(1), dim3(64), 0, stream, partials, nb);
    hipLaunchKernelGGL(scan_write, dim3(nb), dim3(256), 0, stream, deg, partials, row_off, n);
    hipLaunchKernelGGL(bucket_csr, dim3(NB), dim3(256), 0, stream, gcur, recs, row_off, csr, n);

    int gblocks = (n + 63) / 64;
    // layer 1: m = dinv*(x@W1) ; h = bf16(relu(agg(m) + b1))
    hipLaunchKernelGGL((gemm_mfma<1>), dim3(gblocks), dim3(256), 0, stream,
                       (const void*)x, Bhi1, Blo1, dinv, m_bf, n);
    hipLaunchKernelGGL(agg_kernel, dim3((n + 3) / 4), dim3(256), 0, stream,
                       (const unsigned*)m_bf, csr, row_off, deg, dinv, b1, (void*)h_bf, n, 1);
    // layer 2: m = dinv*(h@W2) ; out = agg(m) + b2
    hipLaunchKernelGGL((gemm_mfma<0>), dim3(gblocks), dim3(256), 0, stream,
                       (const void*)h_bf, Bhi2, Blo2, dinv, m_bf, n);
    hipLaunchKernelGGL(agg_kernel, dim3((n + 3) / 4), dim3(256), 0, stream,
                       (const unsigned*)m_bf, csr, row_off, deg, dinv, b2, (void*)out, n, 0);
}

// Round 10
// 236.536 us; speedup vs baseline: 13.3218x; 1.0442x over previous
//
#include <hip/hip_runtime.h>

// ---------------------------------------------------------------------------
// 2-layer GCN forward:  out = A_norm * relu(A_norm * (x@W1) + b1) @ W2 + b2
// A_norm = D^-1/2 (A+I) D^-1/2, applied as dinv[dst] * sum( dinv[src]*m[src] )
// m bf16 row-major [n][128], dinv[src] pre-folded (halves gather traffic).
// agg (R4-proven, FROZEN): wave = 1 dst row, 64-lane coalesced 256B gathers.
// CSR build fused: bucketA -> bscan (1 wave over bucket totals) ->
// bucket_build (LDS-staged recs: hist+scan+scatter in one pass).
// GEMMs on MFMA split-bf16 (hi+lo) for fp32-level accuracy.
// ---------------------------------------------------------------------------

#define RB    9
#define RANGE 512
#define CAPB  16384
#define CHUNK 8192

typedef __attribute__((ext_vector_type(8))) short bf16x8;
typedef __attribute__((ext_vector_type(4))) float f32x4;

__device__ inline float bf_lo(unsigned w) { return __uint_as_float(w << 16); }
__device__ inline float bf_hi(unsigned w) { return __uint_as_float(w & 0xffff0000u); }
__device__ inline unsigned bf16pair(float lo, float hi) {  // RNE pack
    unsigned a = __float_as_uint(lo), b = __float_as_uint(hi);
    a += 0x7fffu + ((a >> 16) & 1u);
    b += 0x7fffu + ((b >> 16) & 1u);
    return (a >> 16) | (b & 0xffff0000u);
}
__device__ inline unsigned short bf16rne(float f) {
    unsigned u = __float_as_uint(f);
    u += 0x7fffu + ((u >> 16) & 1u);
    return (unsigned short)(u >> 16);
}
__device__ inline float bf2f(unsigned short h) { return __uint_as_float(((unsigned)h) << 16); }

__device__ inline void pack_one(int idx, const float* __restrict__ W,
                                uint4* __restrict__ Bhi, uint4* __restrict__ Blo) {
    int lane = idx & 63, ks = (idx >> 6) & 3, nt = idx >> 8;
    int j = nt * 16 + (lane & 15);
    int k0 = ks * 32 + ((lane >> 4) & 3) * 8;
    unsigned hi[4], lo[4];
#pragma unroll
    for (int p = 0; p < 4; p++) {
        float w0 = W[(size_t)(k0 + 2 * p) * 128 + j];
        float w1 = W[(size_t)(k0 + 2 * p + 1) * 128 + j];
        unsigned short h0 = bf16rne(w0), h1 = bf16rne(w1);
        unsigned short l0 = bf16rne(w0 - bf2f(h0)), l1 = bf16rne(w1 - bf2f(h1));
        hi[p] = (unsigned)h0 | ((unsigned)h1 << 16);
        lo[p] = (unsigned)l0 | ((unsigned)l1 << 16);
    }
    Bhi[idx] = make_uint4(hi[0], hi[1], hi[2], hi[3]);
    Blo[idx] = make_uint4(lo[0], lo[1], lo[2], lo[3]);
}

// --- fused setup: detect dtype | init gcur | pack W1,W2 --------------------
__global__ __launch_bounds__(256) void setup(const unsigned* __restrict__ ei, int E,
                                             int* __restrict__ flag,
                                             unsigned* __restrict__ gcur, int NB,
                                             const float* __restrict__ W1,
                                             uint4* __restrict__ Bhi1, uint4* __restrict__ Blo1,
                                             const float* __restrict__ W2,
                                             uint4* __restrict__ Bhi2, uint4* __restrict__ Blo2) {
    const int b = blockIdx.x, t = threadIdx.x;
    if (b == 0) {
        __shared__ int nz;
        if (t == 0) nz = 0;
        __syncthreads();
        int samples = E < 2048 ? E : 2048;
        int cnt = 0;
        for (int i = t; i < samples; i += 256)
            if (ei[2 * i + 1] != 0u) cnt++;
        if (cnt) atomicAdd(&nz, cnt);
        __syncthreads();
        if (t == 0) *flag = (nz == 0) ? 1 : 0;  // all high words zero -> int64
    } else if (b <= 2) {
        int i = (b - 1) * 256 + t;
        if (i < NB) gcur[i] = (unsigned)i * CAPB;
    } else if (b <= 10) {
        pack_one((b - 3) * 256 + t, W1, Bhi1, Blo1);
    } else {
        pack_one((b - 11) * 256 + t, W2, Bhi2, Blo2);
    }
}

// --- phase A: edges -> per-bucket record arrays (4B records) ---------------
__global__ __launch_bounds__(256) void bucketA(const unsigned* __restrict__ ei, int E, int n,
                                               const int* __restrict__ flag,
                                               unsigned* __restrict__ gcur,
                                               unsigned* __restrict__ recs) {
    __shared__ unsigned hist[512];
    __shared__ unsigned offs[512];
    const int t = threadIdx.x;
    const int NB = (n + RANGE - 1) >> RB;
    for (int i = t; i < NB; i += 256) hist[i] = 0u;
    __syncthreads();
    const int base = blockIdx.x * CHUNK;
    const bool i64 = (*flag != 0);
    unsigned rec[32], bk[32];
#pragma unroll
    for (int j = 0; j < 32; j++) {
        int i = base + j * 256 + t;
        unsigned bv = 0xffffffffu, rv = 0u;
        if (i < E) {
            unsigned s, d;
            if (i64) { s = ei[2 * (size_t)i]; d = ei[2 * ((size_t)E + i)]; }
            else     { s = ei[i];             d = ei[(size_t)E + i]; }
            bv = d >> RB;
            rv = (s << RB) | (d & (RANGE - 1));
            atomicAdd(&hist[bv], 1u);
        }
        rec[j] = rv; bk[j] = bv;
    }
    __syncthreads();
    for (int b = t; b < NB; b += 256) {
        unsigned h = hist[b];
        offs[b] = h ? atomicAdd(&gcur[b], h) : 0u;
    }
    __syncthreads();
#pragma unroll
    for (int j = 0; j < 32; j++) {
        unsigned b = bk[j];
        if (b != 0xffffffffu) {
            unsigned pos = atomicAdd(&offs[b], 1u);
            if (pos < (b + 1u) * CAPB) recs[pos] = rec[j];
        }
    }
}

// --- bucket-total exclusive scan (1 wave over NB<=512 buckets) -------------
// total_b = edge-count(gcur) + valid nodes (self-loops)
__global__ void bscan(const unsigned* __restrict__ gcur, unsigned* __restrict__ bbase,
                      int NB, int n) {
    int lane = threadIdx.x;  // 64 threads
    int K = (NB + 63) / 64;
    if (K > 8) K = 8;
    unsigned vals[8];
    unsigned s = 0;
#pragma unroll
    for (int k = 0; k < 8; k++) {
        vals[k] = 0u;
        int b = lane * K + k;
        if (k < K && b < NB) {
            unsigned cnt = gcur[b] - (unsigned)b * CAPB;
            if (cnt > CAPB) cnt = CAPB;
            int valid = n - (b << RB);
            if (valid > RANGE) valid = RANGE;
            if (valid < 0) valid = 0;
            vals[k] = cnt + (unsigned)valid;
        }
        s += vals[k];
    }
    unsigned inc = s;
    for (int o = 1; o < 64; o <<= 1) {
        unsigned u = (unsigned)__shfl_up((int)inc, o, 64);
        if (lane >= o) inc += u;
    }
    unsigned excl = inc - s;
#pragma unroll
    for (int k = 0; k < 8; k++) {
        int b = lane * K + k;
        if (k < K && b < NB) { bbase[b] = excl; excl += vals[k]; }
    }
}

// --- fused CSR build: stage recs in LDS, hist+scan+deg/dinv/row_off+scatter -
__global__ __launch_bounds__(256) void bucket_build(const unsigned* __restrict__ gcur,
                                                    const unsigned* __restrict__ recs,
                                                    const unsigned* __restrict__ bbase,
                                                    unsigned* __restrict__ deg,
                                                    float* __restrict__ dinv,
                                                    int* __restrict__ row_off,
                                                    int* __restrict__ csr, int n) {
    __shared__ unsigned srecs[CAPB];   // 64KB staged records
    __shared__ unsigned hist[RANGE];
    __shared__ unsigned lofs[RANGE];
    __shared__ int cur[RANGE];
    const int b = blockIdx.x, t = threadIdx.x;
    const int node0 = b << RB;
    unsigned base = (unsigned)b * CAPB;
    unsigned cnt = gcur[b] - base; if (cnt > CAPB) cnt = CAPB;
    for (int v = t; v < RANGE; v += 256)
        hist[v] = (node0 + v < n) ? 1u : 0u;   // self-loop
    __syncthreads();
    for (unsigned i = t; i < cnt; i += 256) {
        unsigned r = recs[base + i];
        srecs[i] = r;
        atomicAdd(&hist[r & (RANGE - 1)], 1u);
    }
    __syncthreads();
    if (t < 64) {  // exclusive scan of 512 bins: 64 lanes x 8
        unsigned loc[8], tot = 0;
#pragma unroll
        for (int k = 0; k < 8; k++) { unsigned h = hist[t * 8 + k]; loc[k] = tot; tot += h; }
        unsigned inc = tot;
        for (int o = 1; o < 64; o <<= 1) {
            unsigned u = (unsigned)__shfl_up((int)inc, o, 64);
            if (t >= o) inc += u;
        }
        unsigned excl = inc - tot;
#pragma unroll
        for (int k = 0; k < 8; k++) lofs[t * 8 + k] = excl + loc[k];
    }
    __syncthreads();
    unsigned bb = bbase[b];
    for (int v = t; v < RANGE; v += 256) {
        int node = node0 + v;
        if (node < n) {
            unsigned d = hist[v];
            int ro = (int)(bb + lofs[v]);
            deg[node] = d;
            dinv[node] = rsqrtf((float)d);
            row_off[node] = ro;
            csr[ro] = node;        // self-loop entry
            cur[v] = ro + 1;
        }
    }
    __syncthreads();
    for (unsigned i = t; i < cnt; i += 256) {
        unsigned r = srecs[i];
        int pos = atomicAdd(&cur[r & (RANGE - 1)], 1);
        csr[pos] = (int)(r >> RB);
    }
}

// --- MFMA GEMM: Mout[M,128](bf16 row-major) = dinv[r] * (A[M,128] @ W) ------
// SPLIT=1: A fp32 row-major (3 mfma terms). SPLIT=0: A bf16 row-major (2).
template <int SPLIT>
__global__ __launch_bounds__(256) void gemm_mfma(const void* __restrict__ Ain,
                                                 const uint4* __restrict__ Bhi,
                                                 const uint4* __restrict__ Blo,
                                                 const float* __restrict__ dinv,
                                                 unsigned short* __restrict__ Mout, int M) {
    __shared__ unsigned short Ahi[64 * 128];
    __shared__ unsigned short Alo[SPLIT ? 64 * 128 : 64];
    const int t = threadIdx.x;
    const int row0 = blockIdx.x * 64;
    char* ah8 = (char*)Ahi;
    char* al8 = (char*)Alo;

    if (SPLIT) {
        const float4* A4 = (const float4*)Ain;
#pragma unroll
        for (int it = 0; it < 4; it++) {
            int i = it * 256 + t;
            int r = i >> 4, c8 = i & 15;
            int gr = row0 + r;
            float4 v0 = make_float4(0.f, 0.f, 0.f, 0.f), v1 = v0;
            if (gr < M) { v0 = A4[(size_t)gr * 32 + c8 * 2]; v1 = A4[(size_t)gr * 32 + c8 * 2 + 1]; }
            float f[8] = {v0.x, v0.y, v0.z, v0.w, v1.x, v1.y, v1.z, v1.w};
            unsigned hp[4], lp[4];
#pragma unroll
            for (int p = 0; p < 4; p++) {
                unsigned short h0 = bf16rne(f[2 * p]), h1 = bf16rne(f[2 * p + 1]);
                unsigned short l0 = bf16rne(f[2 * p] - bf2f(h0));
                unsigned short l1 = bf16rne(f[2 * p + 1] - bf2f(h1));
                hp[p] = (unsigned)h0 | ((unsigned)h1 << 16);
                lp[p] = (unsigned)l0 | ((unsigned)l1 << 16);
            }
            int byte = (r * 256 + c8 * 16) ^ ((r & 7) << 4);
            *(uint4*)(ah8 + byte) = make_uint4(hp[0], hp[1], hp[2], hp[3]);
            *(uint4*)(al8 + byte) = make_uint4(lp[0], lp[1], lp[2], lp[3]);
        }
    } else {
        const uint4* A4 = (const uint4*)Ain;
#pragma unroll
        for (int it = 0; it < 4; it++) {
            int i = it * 256 + t;
            int r = i >> 4, c8 = i & 15;
            int gr = row0 + r;
            uint4 v = make_uint4(0u, 0u, 0u, 0u);
            if (gr < M) v = A4[(size_t)gr * 16 + c8];
            int byte = (r * 256 + c8 * 16) ^ ((r & 7) << 4);
            *(uint4*)(ah8 + byte) = v;
        }
    }
    __syncthreads();

    const int wv = t >> 6, lane = t & 63;
    const int arow = wv * 16 + (lane & 15);
    const int kh = ((lane >> 4) & 3) * 8;
    f32x4 acc[8];
#pragma unroll
    for (int nt = 0; nt < 8; nt++) acc[nt] = (f32x4){0.f, 0.f, 0.f, 0.f};
    float dv[4];
    const int orow0 = row0 + wv * 16 + ((lane >> 4) & 3) * 4;
#pragma unroll
    for (int r = 0; r < 4; r++) {
        int rr = orow0 + r;
        dv[r] = (rr < M) ? dinv[rr] : 0.f;
    }
#pragma unroll
    for (int ks = 0; ks < 4; ks++) {
        int byte = (arow * 256 + (ks * 32 + kh) * 2) ^ ((arow & 7) << 4);
        bf16x8 a_h = *(const bf16x8*)(ah8 + byte);
        bf16x8 a_l;
        if (SPLIT) a_l = *(const bf16x8*)(al8 + byte);
#pragma unroll
        for (int nt = 0; nt < 8; nt++) {
            uint4 bhv = Bhi[(nt * 4 + ks) * 64 + lane];
            uint4 blv = Blo[(nt * 4 + ks) * 64 + lane];
            bf16x8 bh = *(bf16x8*)&bhv;
            bf16x8 bl = *(bf16x8*)&blv;
            acc[nt] = __builtin_amdgcn_mfma_f32_16x16x32_bf16(a_h, bh, acc[nt], 0, 0, 0);
            if (SPLIT) acc[nt] = __builtin_amdgcn_mfma_f32_16x16x32_bf16(a_l, bh, acc[nt], 0, 0, 0);
            acc[nt] = __builtin_amdgcn_mfma_f32_16x16x32_bf16(a_h, bl, acc[nt], 0, 0, 0);
        }
    }
    __syncthreads();
    // epilogue: acc -> (bf16 * dinv) via LDS transpose -> coalesced stores
#pragma unroll
    for (int nt = 0; nt < 8; nt++) {
#pragma unroll
        for (int r = 0; r < 4; r++) {
            int lr = wv * 16 + ((lane >> 4) & 3) * 4 + r;
            int byte = (lr * 256 + (nt * 16 + (lane & 15)) * 2) ^ ((lr & 7) << 4);
            *(unsigned short*)(ah8 + byte) = bf16rne(acc[nt][r] * dv[r]);
        }
    }
    __syncthreads();
#pragma unroll
    for (int it = 0; it < 4; it++) {
        int i = it * 256 + t;
        int r = i >> 4, c8 = i & 15;
        int gr = row0 + r;
        if (gr < M) {
            int byte = (r * 256 + c8 * 16) ^ ((r & 7) << 4);
            *(uint4*)(Mout + (size_t)gr * 128 + c8 * 8) = *(uint4*)(ah8 + byte);
        }
    }
}

// --- aggregation (R4-proven, FROZEN): out[v] = dinv[v]*sum_{e} m'[src_e]+b --
__global__ __launch_bounds__(256) void agg_kernel(const unsigned* __restrict__ m,
                                                  const int* __restrict__ csr,
                                                  const int* __restrict__ row_off,
                                                  const unsigned* __restrict__ deg,
                                                  const float* __restrict__ dinv,
                                                  const float* __restrict__ bias,
                                                  void* __restrict__ outp, int n, int mode) {
    int wid = threadIdx.x >> 6, lane = threadIdx.x & 63;
    int v = blockIdx.x * 4 + wid;
    if (v >= n) return;
    int start = row_off[v];
    int cnt = (int)deg[v];
    float ax = 0.f, ay = 0.f;
    int e = 0;
    while (e < cnt) {
        int nload = cnt - e;
        if (nload > 64) nload = 64;
        int sv = 0;
        if (lane < nload) sv = csr[start + e + lane];
        int j = 0;
        for (; j + 16 <= nload; j += 16) {
            unsigned w[16];
#pragma unroll
            for (int q = 0; q < 16; q++) {
                int s = __shfl(sv, j + q);
                w[q] = m[(size_t)s * 64 + lane];
            }
#pragma unroll
            for (int q = 0; q < 16; q++) { ax += bf_lo(w[q]); ay += bf_hi(w[q]); }
        }
        if (j + 8 <= nload) {
            unsigned w[8];
#pragma unroll
            for (int q = 0; q < 8; q++) {
                int s = __shfl(sv, j + q);
                w[q] = m[(size_t)s * 64 + lane];
            }
#pragma unroll
            for (int q = 0; q < 8; q++) { ax += bf_lo(w[q]); ay += bf_hi(w[q]); }
            j += 8;
        }
        for (; j < nload; j++) {
            int s = __shfl(sv, j);
            unsigned w = m[(size_t)s * 64 + lane];
            ax += bf_lo(w); ay += bf_hi(w);
        }
        e += nload;
    }
    float dv = dinv[v];
    float2 b = ((const float2*)bias)[lane];
    float ox = fmaf(dv, ax, b.x), oy = fmaf(dv, ay, b.y);
    if (mode) {
        ox = fmaxf(ox, 0.f); oy = fmaxf(oy, 0.f);
        ((unsigned*)outp)[(size_t)v * 64 + lane] = bf16pair(ox, oy);
    } else {
        ((float2*)outp)[(size_t)v * 64 + lane] = make_float2(ox, oy);
    }
}

extern "C" void kernel_launch(void* const* d_in, const int* in_sizes, int n_in,
                              void* d_out, int out_size, void* d_ws, size_t ws_size,
                              hipStream_t stream) {
    const float*    x  = (const float*)d_in[0];
    const float*    W1 = (const float*)d_in[1];
    const float*    b1 = (const float*)d_in[2];
    const float*    W2 = (const float*)d_in[3];
    const float*    b2 = (const float*)d_in[4];
    const unsigned* ei = (const unsigned*)d_in[5];
    int n = in_sizes[0] / 128;
    int E = in_sizes[5] / 2;
    float* out = (float*)d_out;
    int NB = (n + RANGE - 1) >> RB;

    char* w = (char*)d_ws;
    size_t off = 0;
    auto alloc = [&](size_t bytes) -> void* {
        void* p = w + off;
        off = (off + bytes + 255) & ~(size_t)255;
        return p;
    };
    int*            flag     = (int*)alloc(4);
    unsigned*       deg      = (unsigned*)alloc((size_t)n * 4);
    float*          dinv     = (float*)alloc((size_t)n * 4);
    int*            row_off  = (int*)alloc((size_t)(n + 1) * 4);
    unsigned*       bbase    = (unsigned*)alloc(512 * 4);
    unsigned*       gcur     = (unsigned*)alloc(512 * 4);
    uint4*          Bhi1     = (uint4*)alloc(2048 * 16);
    uint4*          Blo1     = (uint4*)alloc(2048 * 16);
    uint4*          Bhi2     = (uint4*)alloc(2048 * 16);
    uint4*          Blo2     = (uint4*)alloc(2048 * 16);
    unsigned*       recs     = (unsigned*)alloc((size_t)NB * CAPB * 4);
    int*            csr      = (int*)alloc((size_t)(E + n + 64) * 4);
    unsigned short* m_bf     = (unsigned short*)alloc((size_t)n * 128 * 2);
    unsigned*       h_bf     = (unsigned*)alloc((size_t)n * 64 * 4);
    (void)ws_size; (void)n_in; (void)out_size;

    int nchunk = (E + CHUNK - 1) / CHUNK;

    hipLaunchKernelGGL(setup, dim3(19), dim3(256), 0, stream,
                       ei, E, flag, gcur, NB, W1, Bhi1, Blo1, W2, Bhi2, Blo2);
    hipLaunchKernelGGL(bucketA, dim3(nchunk), dim3(256), 0, stream, ei, E, n, flag, gcur, recs);
    hipLaunchKernelGGL(bscan, dim3(1), dim3(64), 0, stream, gcur, bbase, NB, n);
    hipLaunchKernelGGL(bucket_build, dim3(NB), dim3(256), 0, stream,
                       gcur, recs, bbase, deg, dinv, row_off, csr, n);

    int gblocks = (n + 63) / 64;
    // layer 1: m = dinv*(x@W1) ; h = bf16(relu(agg(m) + b1))
    hipLaunchKernelGGL((gemm_mfma<1>), dim3(gblocks), dim3(256), 0, stream,
                       (const void*)x, Bhi1, Blo1, dinv, m_bf, n);
    hipLaunchKernelGGL(agg_kernel, dim3((n + 3) / 4), dim3(256), 0, stream,
                       (const unsigned*)m_bf, csr, row_off, deg, dinv, b1, (void*)h_bf, n, 1);
    // layer 2: m = dinv*(h@W2) ; out = agg(m) + b2
    hipLaunchKernelGGL((gemm_mfma<0>), dim3(gblocks), dim3(256), 0, stream,
                       (const void*)h_bf, Bhi2, Blo2, dinv, m_bf, n);
    hipLaunchKernelGGL(agg_kernel, dim3((n + 3) / 4), dim3(256), 0, stream,
                       (const unsigned*)m_bf, csr, row_off, deg, dinv, b2, (void*)out, n, 0);
}

// Round 11
// 223.112 us; speedup vs baseline: 14.1233x; 1.0602x over previous
//
#include <hip/hip_runtime.h>

// ---------------------------------------------------------------------------
// 2-layer GCN forward:  out = A_norm * relu(A_norm * (x@W1) + b1) @ W2 + b2
// A_norm = D^-1/2 (A+I) D^-1/2, applied as dinv[dst] * sum( dinv[src]*m[src] )
// m bf16 row-major [n][128], dinv[src] pre-folded (halves gather traffic).
// agg (R4-proven, FROZEN): wave = 1 dst row, 64-lane coalesced 256B gathers.
// CSR build fused: bucketA -> bscan -> bucket_build (LDS-staged, one pass).
// GEMM: MFMA split-bf16; B-fragments REGISTER-RESIDENT per wave (was 512
// uint4 global loads/wave -> 16), wave owns 32 cols x all 64 rows in 4 chunks.
// ---------------------------------------------------------------------------

#define RB    9
#define RANGE 512
#define CAPB  16384
#define CHUNK 8192

typedef __attribute__((ext_vector_type(8))) short bf16x8;
typedef __attribute__((ext_vector_type(4))) float f32x4;

__device__ inline float bf_lo(unsigned w) { return __uint_as_float(w << 16); }
__device__ inline float bf_hi(unsigned w) { return __uint_as_float(w & 0xffff0000u); }
__device__ inline unsigned bf16pair(float lo, float hi) {  // RNE pack
    unsigned a = __float_as_uint(lo), b = __float_as_uint(hi);
    a += 0x7fffu + ((a >> 16) & 1u);
    b += 0x7fffu + ((b >> 16) & 1u);
    return (a >> 16) | (b & 0xffff0000u);
}
__device__ inline unsigned short bf16rne(float f) {
    unsigned u = __float_as_uint(f);
    u += 0x7fffu + ((u >> 16) & 1u);
    return (unsigned short)(u >> 16);
}
__device__ inline float bf2f(unsigned short h) { return __uint_as_float(((unsigned)h) << 16); }

__device__ inline void pack_one(int idx, const float* __restrict__ W,
                                uint4* __restrict__ Bhi, uint4* __restrict__ Blo) {
    int lane = idx & 63, ks = (idx >> 6) & 3, nt = idx >> 8;
    int j = nt * 16 + (lane & 15);
    int k0 = ks * 32 + ((lane >> 4) & 3) * 8;
    unsigned hi[4], lo[4];
#pragma unroll
    for (int p = 0; p < 4; p++) {
        float w0 = W[(size_t)(k0 + 2 * p) * 128 + j];
        float w1 = W[(size_t)(k0 + 2 * p + 1) * 128 + j];
        unsigned short h0 = bf16rne(w0), h1 = bf16rne(w1);
        unsigned short l0 = bf16rne(w0 - bf2f(h0)), l1 = bf16rne(w1 - bf2f(h1));
        hi[p] = (unsigned)h0 | ((unsigned)h1 << 16);
        lo[p] = (unsigned)l0 | ((unsigned)l1 << 16);
    }
    Bhi[idx] = make_uint4(hi[0], hi[1], hi[2], hi[3]);
    Blo[idx] = make_uint4(lo[0], lo[1], lo[2], lo[3]);
}

// --- fused setup: detect dtype | init gcur | pack W1,W2 --------------------
__global__ __launch_bounds__(256) void setup(const unsigned* __restrict__ ei, int E,
                                             int* __restrict__ flag,
                                             unsigned* __restrict__ gcur, int NB,
                                             const float* __restrict__ W1,
                                             uint4* __restrict__ Bhi1, uint4* __restrict__ Blo1,
                                             const float* __restrict__ W2,
                                             uint4* __restrict__ Bhi2, uint4* __restrict__ Blo2) {
    const int b = blockIdx.x, t = threadIdx.x;
    if (b == 0) {
        __shared__ int nz;
        if (t == 0) nz = 0;
        __syncthreads();
        int samples = E < 2048 ? E : 2048;
        int cnt = 0;
        for (int i = t; i < samples; i += 256)
            if (ei[2 * i + 1] != 0u) cnt++;
        if (cnt) atomicAdd(&nz, cnt);
        __syncthreads();
        if (t == 0) *flag = (nz == 0) ? 1 : 0;  // all high words zero -> int64
    } else if (b <= 2) {
        int i = (b - 1) * 256 + t;
        if (i < NB) gcur[i] = (unsigned)i * CAPB;
    } else if (b <= 10) {
        pack_one((b - 3) * 256 + t, W1, Bhi1, Blo1);
    } else {
        pack_one((b - 11) * 256 + t, W2, Bhi2, Blo2);
    }
}

// --- phase A: edges -> per-bucket record arrays (4B records) ---------------
__global__ __launch_bounds__(256) void bucketA(const unsigned* __restrict__ ei, int E, int n,
                                               const int* __restrict__ flag,
                                               unsigned* __restrict__ gcur,
                                               unsigned* __restrict__ recs) {
    __shared__ unsigned hist[512];
    __shared__ unsigned offs[512];
    const int t = threadIdx.x;
    const int NB = (n + RANGE - 1) >> RB;
    for (int i = t; i < NB; i += 256) hist[i] = 0u;
    __syncthreads();
    const int base = blockIdx.x * CHUNK;
    const bool i64 = (*flag != 0);
    unsigned rec[32], bk[32];
#pragma unroll
    for (int j = 0; j < 32; j++) {
        int i = base + j * 256 + t;
        unsigned bv = 0xffffffffu, rv = 0u;
        if (i < E) {
            unsigned s, d;
            if (i64) { s = ei[2 * (size_t)i]; d = ei[2 * ((size_t)E + i)]; }
            else     { s = ei[i];             d = ei[(size_t)E + i]; }
            bv = d >> RB;
            rv = (s << RB) | (d & (RANGE - 1));
            atomicAdd(&hist[bv], 1u);
        }
        rec[j] = rv; bk[j] = bv;
    }
    __syncthreads();
    for (int b = t; b < NB; b += 256) {
        unsigned h = hist[b];
        offs[b] = h ? atomicAdd(&gcur[b], h) : 0u;
    }
    __syncthreads();
#pragma unroll
    for (int j = 0; j < 32; j++) {
        unsigned b = bk[j];
        if (b != 0xffffffffu) {
            unsigned pos = atomicAdd(&offs[b], 1u);
            if (pos < (b + 1u) * CAPB) recs[pos] = rec[j];
        }
    }
}

// --- bucket-total exclusive scan (1 wave over NB<=512 buckets) -------------
__global__ void bscan(const unsigned* __restrict__ gcur, unsigned* __restrict__ bbase,
                      int NB, int n) {
    int lane = threadIdx.x;  // 64 threads
    int K = (NB + 63) / 64;
    if (K > 8) K = 8;
    unsigned vals[8];
    unsigned s = 0;
#pragma unroll
    for (int k = 0; k < 8; k++) {
        vals[k] = 0u;
        int b = lane * K + k;
        if (k < K && b < NB) {
            unsigned cnt = gcur[b] - (unsigned)b * CAPB;
            if (cnt > CAPB) cnt = CAPB;
            int valid = n - (b << RB);
            if (valid > RANGE) valid = RANGE;
            if (valid < 0) valid = 0;
            vals[k] = cnt + (unsigned)valid;
        }
        s += vals[k];
    }
    unsigned inc = s;
    for (int o = 1; o < 64; o <<= 1) {
        unsigned u = (unsigned)__shfl_up((int)inc, o, 64);
        if (lane >= o) inc += u;
    }
    unsigned excl = inc - s;
#pragma unroll
    for (int k = 0; k < 8; k++) {
        int b = lane * K + k;
        if (k < K && b < NB) { bbase[b] = excl; excl += vals[k]; }
    }
}

// --- fused CSR build: stage recs in LDS, hist+scan+deg/dinv/row_off+scatter -
__global__ __launch_bounds__(256) void bucket_build(const unsigned* __restrict__ gcur,
                                                    const unsigned* __restrict__ recs,
                                                    const unsigned* __restrict__ bbase,
                                                    unsigned* __restrict__ deg,
                                                    float* __restrict__ dinv,
                                                    int* __restrict__ row_off,
                                                    int* __restrict__ csr, int n) {
    __shared__ unsigned srecs[CAPB];   // 64KB staged records
    __shared__ unsigned hist[RANGE];
    __shared__ unsigned lofs[RANGE];
    __shared__ int cur[RANGE];
    const int b = blockIdx.x, t = threadIdx.x;
    const int node0 = b << RB;
    unsigned base = (unsigned)b * CAPB;
    unsigned cnt = gcur[b] - base; if (cnt > CAPB) cnt = CAPB;
    for (int v = t; v < RANGE; v += 256)
        hist[v] = (node0 + v < n) ? 1u : 0u;   // self-loop
    __syncthreads();
    for (unsigned i = t; i < cnt; i += 256) {
        unsigned r = recs[base + i];
        srecs[i] = r;
        atomicAdd(&hist[r & (RANGE - 1)], 1u);
    }
    __syncthreads();
    if (t < 64) {  // exclusive scan of 512 bins: 64 lanes x 8
        unsigned loc[8], tot = 0;
#pragma unroll
        for (int k = 0; k < 8; k++) { unsigned h = hist[t * 8 + k]; loc[k] = tot; tot += h; }
        unsigned inc = tot;
        for (int o = 1; o < 64; o <<= 1) {
            unsigned u = (unsigned)__shfl_up((int)inc, o, 64);
            if (t >= o) inc += u;
        }
        unsigned excl = inc - tot;
#pragma unroll
        for (int k = 0; k < 8; k++) lofs[t * 8 + k] = excl + loc[k];
    }
    __syncthreads();
    unsigned bb = bbase[b];
    for (int v = t; v < RANGE; v += 256) {
        int node = node0 + v;
        if (node < n) {
            unsigned d = hist[v];
            int ro = (int)(bb + lofs[v]);
            deg[node] = d;
            dinv[node] = rsqrtf((float)d);
            row_off[node] = ro;
            csr[ro] = node;        // self-loop entry
            cur[v] = ro + 1;
        }
    }
    __syncthreads();
    for (unsigned i = t; i < cnt; i += 256) {
        unsigned r = srecs[i];
        int pos = atomicAdd(&cur[r & (RANGE - 1)], 1);
        csr[pos] = (int)(r >> RB);
    }
}

// --- MFMA GEMM: Mout[M,128](bf16) = dinv[r] * (A[M,128] @ W) ----------------
// B register-resident: wave w owns cols [w*32, w*32+32) (nt = 2w, 2w+1),
// preloads its 16 B-fragments once, loops 4 row-chunks of 16 reading A (LDS).
// SPLIT=1: A fp32 row-major (3 mfma terms). SPLIT=0: A bf16 row-major (2).
template <int SPLIT>
__global__ __launch_bounds__(256) void gemm_mfma(const void* __restrict__ Ain,
                                                 const uint4* __restrict__ Bhi,
                                                 const uint4* __restrict__ Blo,
                                                 const float* __restrict__ dinv,
                                                 unsigned short* __restrict__ Mout, int M) {
    __shared__ unsigned short Ahi[64 * 128];
    __shared__ unsigned short Alo[SPLIT ? 64 * 128 : 64];
    __shared__ unsigned short Cst[16 * 136];  // chunk epilogue staging (pad 8)
    const int t = threadIdx.x;
    const int row0 = blockIdx.x * 64;
    char* ah8 = (char*)Ahi;
    char* al8 = (char*)Alo;

    if (SPLIT) {
        const float4* A4 = (const float4*)Ain;
#pragma unroll
        for (int it = 0; it < 4; it++) {
            int i = it * 256 + t;
            int r = i >> 4, c8 = i & 15;
            int gr = row0 + r;
            float4 v0 = make_float4(0.f, 0.f, 0.f, 0.f), v1 = v0;
            if (gr < M) { v0 = A4[(size_t)gr * 32 + c8 * 2]; v1 = A4[(size_t)gr * 32 + c8 * 2 + 1]; }
            float f[8] = {v0.x, v0.y, v0.z, v0.w, v1.x, v1.y, v1.z, v1.w};
            unsigned hp[4], lp[4];
#pragma unroll
            for (int p = 0; p < 4; p++) {
                unsigned short h0 = bf16rne(f[2 * p]), h1 = bf16rne(f[2 * p + 1]);
                unsigned short l0 = bf16rne(f[2 * p] - bf2f(h0));
                unsigned short l1 = bf16rne(f[2 * p + 1] - bf2f(h1));
                hp[p] = (unsigned)h0 | ((unsigned)h1 << 16);
                lp[p] = (unsigned)l0 | ((unsigned)l1 << 16);
            }
            int byte = (r * 256 + c8 * 16) ^ ((r & 7) << 4);
            *(uint4*)(ah8 + byte) = make_uint4(hp[0], hp[1], hp[2], hp[3]);
            *(uint4*)(al8 + byte) = make_uint4(lp[0], lp[1], lp[2], lp[3]);
        }
    } else {
        const uint4* A4 = (const uint4*)Ain;
#pragma unroll
        for (int it = 0; it < 4; it++) {
            int i = it * 256 + t;
            int r = i >> 4, c8 = i & 15;
            int gr = row0 + r;
            uint4 v = make_uint4(0u, 0u, 0u, 0u);
            if (gr < M) v = A4[(size_t)gr * 16 + c8];
            int byte = (r * 256 + c8 * 16) ^ ((r & 7) << 4);
            *(uint4*)(ah8 + byte) = v;
        }
    }

    const int wv = t >> 6, lane = t & 63;
    const int kh = ((lane >> 4) & 3) * 8;
    const int lr0 = ((lane >> 4) & 3) * 4;   // local row group within chunk
    // preload this wave's 16 B fragments (cols nt = 2*wv, 2*wv+1)
    uint4 bhv[2][4], blv[2][4];
#pragma unroll
    for (int p = 0; p < 2; p++)
#pragma unroll
        for (int ks = 0; ks < 4; ks++) {
            int nt = wv * 2 + p;
            bhv[p][ks] = Bhi[(nt * 4 + ks) * 64 + lane];
            blv[p][ks] = Blo[(nt * 4 + ks) * 64 + lane];
        }
    __syncthreads();   // A staged

#pragma unroll
    for (int c = 0; c < 4; c++) {
        f32x4 acc[2];
        acc[0] = (f32x4){0.f, 0.f, 0.f, 0.f};
        acc[1] = (f32x4){0.f, 0.f, 0.f, 0.f};
        const int arow = c * 16 + (lane & 15);
#pragma unroll
        for (int ks = 0; ks < 4; ks++) {
            int byte = (arow * 256 + (ks * 32 + kh) * 2) ^ ((arow & 7) << 4);
            bf16x8 a_h = *(const bf16x8*)(ah8 + byte);
            bf16x8 a_l;
            if (SPLIT) a_l = *(const bf16x8*)(al8 + byte);
#pragma unroll
            for (int p = 0; p < 2; p++) {
                bf16x8 bh = *(bf16x8*)&bhv[p][ks];
                bf16x8 bl = *(bf16x8*)&blv[p][ks];
                acc[p] = __builtin_amdgcn_mfma_f32_16x16x32_bf16(a_h, bh, acc[p], 0, 0, 0);
                if (SPLIT) acc[p] = __builtin_amdgcn_mfma_f32_16x16x32_bf16(a_l, bh, acc[p], 0, 0, 0);
                acc[p] = __builtin_amdgcn_mfma_f32_16x16x32_bf16(a_h, bl, acc[p], 0, 0, 0);
            }
        }
        // fold dinv, stage chunk (16 rows x 128 cols) for coalesced store
        float dvr[4];
#pragma unroll
        for (int r = 0; r < 4; r++) {
            int grow = row0 + c * 16 + lr0 + r;
            dvr[r] = (grow < M) ? dinv[grow] : 0.f;
        }
#pragma unroll
        for (int p = 0; p < 2; p++) {
            int nt = wv * 2 + p;
#pragma unroll
            for (int r = 0; r < 4; r++)
                Cst[(lr0 + r) * 136 + nt * 16 + (lane & 15)] = bf16rne(acc[p][r] * dvr[r]);
        }
        __syncthreads();
        {
            int r = t >> 4, c8 = t & 15;
            int gr = row0 + c * 16 + r;
            if (gr < M)
                *(uint4*)(Mout + (size_t)gr * 128 + c8 * 8) = *(uint4*)&Cst[r * 136 + c8 * 8];
        }
        __syncthreads();
    }
}

// --- aggregation (R4-proven, FROZEN): out[v] = dinv[v]*sum_{e} m'[src_e]+b --
__global__ __launch_bounds__(256) void agg_kernel(const unsigned* __restrict__ m,
                                                  const int* __restrict__ csr,
                                                  const int* __restrict__ row_off,
                                                  const unsigned* __restrict__ deg,
                                                  const float* __restrict__ dinv,
                                                  const float* __restrict__ bias,
                                                  void* __restrict__ outp, int n, int mode) {
    int wid = threadIdx.x >> 6, lane = threadIdx.x & 63;
    int v = blockIdx.x * 4 + wid;
    if (v >= n) return;
    int start = row_off[v];
    int cnt = (int)deg[v];
    float ax = 0.f, ay = 0.f;
    int e = 0;
    while (e < cnt) {
        int nload = cnt - e;
        if (nload > 64) nload = 64;
        int sv = 0;
        if (lane < nload) sv = csr[start + e + lane];
        int j = 0;
        for (; j + 16 <= nload; j += 16) {
            unsigned w[16];
#pragma unroll
            for (int q = 0; q < 16; q++) {
                int s = __shfl(sv, j + q);
                w[q] = m[(size_t)s * 64 + lane];
            }
#pragma unroll
            for (int q = 0; q < 16; q++) { ax += bf_lo(w[q]); ay += bf_hi(w[q]); }
        }
        if (j + 8 <= nload) {
            unsigned w[8];
#pragma unroll
            for (int q = 0; q < 8; q++) {
                int s = __shfl(sv, j + q);
                w[q] = m[(size_t)s * 64 + lane];
            }
#pragma unroll
            for (int q = 0; q < 8; q++) { ax += bf_lo(w[q]); ay += bf_hi(w[q]); }
            j += 8;
        }
        for (; j < nload; j++) {
            int s = __shfl(sv, j);
            unsigned w = m[(size_t)s * 64 + lane];
            ax += bf_lo(w); ay += bf_hi(w);
        }
        e += nload;
    }
    float dv = dinv[v];
    float2 b = ((const float2*)bias)[lane];
    float ox = fmaf(dv, ax, b.x), oy = fmaf(dv, ay, b.y);
    if (mode) {
        ox = fmaxf(ox, 0.f); oy = fmaxf(oy, 0.f);
        ((unsigned*)outp)[(size_t)v * 64 + lane] = bf16pair(ox, oy);
    } else {
        ((float2*)outp)[(size_t)v * 64 + lane] = make_float2(ox, oy);
    }
}

extern "C" void kernel_launch(void* const* d_in, const int* in_sizes, int n_in,
                              void* d_out, int out_size, void* d_ws, size_t ws_size,
                              hipStream_t stream) {
    const float*    x  = (const float*)d_in[0];
    const float*    W1 = (const float*)d_in[1];
    const float*    b1 = (const float*)d_in[2];
    const float*    W2 = (const float*)d_in[3];
    const float*    b2 = (const float*)d_in[4];
    const unsigned* ei = (const unsigned*)d_in[5];
    int n = in_sizes[0] / 128;
    int E = in_sizes[5] / 2;
    float* out = (float*)d_out;
    int NB = (n + RANGE - 1) >> RB;

    char* w = (char*)d_ws;
    size_t off = 0;
    auto alloc = [&](size_t bytes) -> void* {
        void* p = w + off;
        off = (off + bytes + 255) & ~(size_t)255;
        return p;
    };
    int*            flag     = (int*)alloc(4);
    unsigned*       deg      = (unsigned*)alloc((size_t)n * 4);
    float*          dinv     = (float*)alloc((size_t)n * 4);
    int*            row_off  = (int*)alloc((size_t)(n + 1) * 4);
    unsigned*       bbase    = (unsigned*)alloc(512 * 4);
    unsigned*       gcur     = (unsigned*)alloc(512 * 4);
    uint4*          Bhi1     = (uint4*)alloc(2048 * 16);
    uint4*          Blo1     = (uint4*)alloc(2048 * 16);
    uint4*          Bhi2     = (uint4*)alloc(2048 * 16);
    uint4*          Blo2     = (uint4*)alloc(2048 * 16);
    unsigned*       recs     = (unsigned*)alloc((size_t)NB * CAPB * 4);
    int*            csr      = (int*)alloc((size_t)(E + n + 64) * 4);
    unsigned short* m_bf     = (unsigned short*)alloc((size_t)n * 128 * 2);
    unsigned*       h_bf     = (unsigned*)alloc((size_t)n * 64 * 4);
    (void)ws_size; (void)n_in; (void)out_size;

    int nchunk = (E + CHUNK - 1) / CHUNK;

    hipLaunchKernelGGL(setup, dim3(19), dim3(256), 0, stream,
                       ei, E, flag, gcur, NB, W1, Bhi1, Blo1, W2, Bhi2, Blo2);
    hipLaunchKernelGGL(bucketA, dim3(nchunk), dim3(256), 0, stream, ei, E, n, flag, gcur, recs);
    hipLaunchKernelGGL(bscan, dim3(1), dim3(64), 0, stream, gcur, bbase, NB, n);
    hipLaunchKernelGGL(bucket_build, dim3(NB), dim3(256), 0, stream,
                       gcur, recs, bbase, deg, dinv, row_off, csr, n);

    int gblocks = (n + 63) / 64;
    // layer 1: m = dinv*(x@W1) ; h = bf16(relu(agg(m) + b1))
    hipLaunchKernelGGL((gemm_mfma<1>), dim3(gblocks), dim3(256), 0, stream,
                       (const void*)x, Bhi1, Blo1, dinv, m_bf, n);
    hipLaunchKernelGGL(agg_kernel, dim3((n + 3) / 4), dim3(256), 0, stream,
                       (const unsigned*)m_bf, csr, row_off, deg, dinv, b1, (void*)h_bf, n, 1);
    // layer 2: m = dinv*(h@W2) ; out = agg(m) + b2
    hipLaunchKernelGGL((gemm_mfma<0>), dim3(gblocks), dim3(256), 0, stream,
                       (const void*)h_bf, Bhi2, Blo2, dinv, m_bf, n);
    hipLaunchKernelGGL(agg_kernel, dim3((n + 3) / 4), dim3(256), 0, stream,
                       (const unsigned*)m_bf, csr, row_off, deg, dinv, b2, (void*)out, n, 0);
}